// Round 1
// baseline (656.905 us; speedup 1.0000x reference)
//
#include <hip/hip_runtime.h>
#include <stdint.h>

typedef unsigned short u16;

#define MROWS 2048
#define DA 768
#define DT 512
#define NV 49408
#define VSPLIT 8
#define VSLICE (NV / VSPLIT)   // 6176
#define NT 32
#define NITER (VSLICE / NT)    // 193

typedef __attribute__((ext_vector_type(4))) float f32x4;
typedef __attribute__((ext_vector_type(8))) __bf16 bf16x8;

__device__ __forceinline__ u16 f2bf(float f) {
  uint32_t u = __builtin_bit_cast(uint32_t, f);
  u += 0x7FFFu + ((u >> 16) & 1u);
  return (u16)(u >> 16);
}

__device__ __forceinline__ void gload16(void* g, void* l) {
  __builtin_amdgcn_global_load_lds((__attribute__((address_space(1))) void*)g,
                                   (__attribute__((address_space(3))) void*)l,
                                   16, 0, 0);
}

// ---------------- proj = audio @ W + b (fp32, 64x64 tile) ----------------
__global__ __launch_bounds__(256) void k_proj(const float* __restrict__ A,
                                              const float* __restrict__ W,
                                              const float* __restrict__ bias,
                                              float* __restrict__ P) {
  __shared__ float As[16][72];
  __shared__ float Bs[16][72];
  const int m0 = blockIdx.x * 64, n0 = blockIdx.y * 64;
  const int t = threadIdx.x;
  const int ty = t >> 4, tx = t & 15;
  const int ar = t >> 2, ak = (t & 3) * 4;
  const int bk = t >> 4, bn = (t & 15) * 4;
  float acc[4][4] = {};
  for (int k0 = 0; k0 < DA; k0 += 16) {
    float4 av = *(const float4*)&A[(size_t)(m0 + ar) * DA + k0 + ak];
    float4 bv = *(const float4*)&W[(size_t)(k0 + bk) * DT + n0 + bn];
    __syncthreads();
    As[ak + 0][ar] = av.x; As[ak + 1][ar] = av.y;
    As[ak + 2][ar] = av.z; As[ak + 3][ar] = av.w;
    *(float4*)&Bs[bk][bn] = bv;
    __syncthreads();
#pragma unroll
    for (int kk = 0; kk < 16; ++kk) {
      float4 a4 = *(const float4*)&As[kk][ty * 4];
      float4 b4 = *(const float4*)&Bs[kk][tx * 4];
      float ae[4] = {a4.x, a4.y, a4.z, a4.w};
      float be[4] = {b4.x, b4.y, b4.z, b4.w};
#pragma unroll
      for (int i = 0; i < 4; ++i)
#pragma unroll
        for (int j = 0; j < 4; ++j) acc[i][j] = fmaf(ae[i], be[j], acc[i][j]);
    }
  }
#pragma unroll
  for (int i = 0; i < 4; ++i) {
    int row = m0 + ty * 4 + i;
    float4 o;
    o.x = acc[i][0] + bias[n0 + tx * 4 + 0];
    o.y = acc[i][1] + bias[n0 + tx * 4 + 1];
    o.z = acc[i][2] + bias[n0 + tx * 4 + 2];
    o.w = acc[i][3] + bias[n0 + tx * 4 + 3];
    *(float4*)&P[(size_t)row * DT + n0 + tx * 4] = o;
  }
}

// ---------------- BN stats: partial sums (deterministic, no atomics) -----
__global__ __launch_bounds__(256) void k_stats(const float* __restrict__ P,
                                               float* __restrict__ pstat) {
  const int t = threadIdx.x;
  const int r0 = blockIdx.x * 32;
  float s0 = 0, q0 = 0, s1 = 0, q1 = 0;
  for (int r = r0; r < r0 + 32; ++r) {
    float x0 = P[(size_t)r * DT + t];
    float x1 = P[(size_t)r * DT + t + 256];
    s0 += x0; q0 += x0 * x0; s1 += x1; q1 += x1 * x1;
  }
  float* d = pstat + (size_t)blockIdx.x * 1024;
  d[t] = s0; d[t + 256] = s1; d[512 + t] = q0; d[768 + t] = q1;
}

__global__ __launch_bounds__(256) void k_stats2(const float* __restrict__ pstat,
                                                float* __restrict__ stats) {
  int c = blockIdx.x * 256 + threadIdx.x;  // 0..1023
  float s = 0.f;
  for (int b = 0; b < 64; ++b) s += pstat[(size_t)b * 1024 + c];
  stats[c] = s;
}

// ---------------- BN apply + row L2 normalize -> bnn (bf16) --------------
__global__ __launch_bounds__(64) void k_bnnorm(const float* __restrict__ P,
                                               const float* __restrict__ stats,
                                               const float* __restrict__ gamma,
                                               const float* __restrict__ beta,
                                               u16* __restrict__ bnn) {
  const int r = blockIdx.x, l = threadIdx.x;
  float v[8];
  float ss = 0.f;
#pragma unroll
  for (int i = 0; i < 8; ++i) {
    int c = l * 8 + i;
    float mean = stats[c] * (1.f / MROWS);
    float var = stats[DT + c] * (1.f / MROWS) - mean * mean;
    float is = rsqrtf(var + 1e-5f);
    float x = (P[(size_t)r * DT + c] - mean) * is * gamma[c] + beta[c];
    v[i] = x; ss += x * x;
  }
#pragma unroll
  for (int off = 32; off > 0; off >>= 1) ss += __shfl_xor(ss, off);
  float rn = rsqrtf(ss);
  union { u16 u[8]; int4 q; } pk;
#pragma unroll
  for (int i = 0; i < 8; ++i) pk.u[i] = f2bf(v[i] * rn);
  *(int4*)&bnn[(size_t)r * DT + l * 8] = pk.q;
}

// ---------------- emb -> bf16 rows + inv_norm*10 -------------------------
__global__ __launch_bounds__(256) void k_embprep(const float* __restrict__ emb,
                                                 u16* __restrict__ embB,
                                                 float* __restrict__ invn) {
  const int w = threadIdx.x >> 6, l = threadIdx.x & 63;
  const int vrow = blockIdx.x * 4 + w;
  const float* src = emb + (size_t)vrow * DT + l * 8;
  float4 a = *(const float4*)src;
  float4 b = *(const float4*)(src + 4);
  float x[8] = {a.x, a.y, a.z, a.w, b.x, b.y, b.z, b.w};
  float ss = 0.f;
#pragma unroll
  for (int i = 0; i < 8; ++i) ss += x[i] * x[i];
#pragma unroll
  for (int off = 32; off > 0; off >>= 1) ss += __shfl_xor(ss, off);
  if (l == 0) invn[vrow] = rsqrtf(ss) * 10.0f;  // 1/||emb_v|| * (1/T)
  union { u16 u[8]; int4 q; } pk;
#pragma unroll
  for (int i = 0; i < 8; ++i) pk.u[i] = f2bf(x[i]);
  *(int4*)&embB[(size_t)vrow * DT + l * 8] = pk.q;
}

// ---------------- embT[d][v] = bf16(emb[v][d]) ---------------------------
__global__ __launch_bounds__(256) void k_embT(const float* __restrict__ emb,
                                              u16* __restrict__ embT) {
  __shared__ float tile[64][65];
  const int v0 = blockIdx.x * 64, d0 = blockIdx.y * 64;
  const int t = threadIdx.x;
  {
    const int r = t >> 4, c = (t & 15) * 4;
#pragma unroll
    for (int i = 0; i < 4; ++i) {
      float4 x = *(const float4*)&emb[(size_t)(v0 + r + i * 16) * DT + d0 + c];
      tile[r + i * 16][c + 0] = x.x; tile[r + i * 16][c + 1] = x.y;
      tile[r + i * 16][c + 2] = x.z; tile[r + i * 16][c + 3] = x.w;
    }
  }
  __syncthreads();
  {
    const int d = t >> 2;
    const int vc = (t & 3) * 16;
    union { u16 u[8]; int4 q; } p0, p1;
#pragma unroll
    for (int i = 0; i < 8; ++i) p0.u[i] = f2bf(tile[vc + i][d]);
#pragma unroll
    for (int i = 0; i < 8; ++i) p1.u[i] = f2bf(tile[vc + 8 + i][d]);
    u16* dst = embT + (size_t)(d0 + d) * NV + v0 + vc;
    *(int4*)dst = p0.q;
    *(int4*)(dst + 8) = p1.q;
  }
}

// ---------------- fused cos->softmax->PV flash over vocab ----------------
// grid (32 row-tiles of 64, VSPLIT).  4 waves/block, each wave owns 16 rows.
__global__ __launch_bounds__(256, 1) void k_flash(const u16* __restrict__ bnn,
                                                  const u16* __restrict__ embB,
                                                  const u16* __restrict__ embT,
                                                  const float* __restrict__ invn,
                                                  float* __restrict__ pacc,
                                                  float* __restrict__ pml) {
  extern __shared__ char smem[];
  char* ekb = smem;            // [32 rows][1024B], XOR-swizzled (granule ^ (v&7))
  char* evb = smem + 32768;    // [512 rows][64B],  XOR-swizzled (granule ^ swz4(d))
  char* plb = smem + 65536;    // per-wave P bounce [16][80B]
  const int t = threadIdx.x;
  const int w = t >> 6, l = t & 63;
  const int lr = l & 15, lg = l >> 4;
  const int mg = blockIdx.x, vs = blockIdx.y;
  const int r0 = mg * 64 + w * 16;
  const int vbase = vs * VSLICE;
  char* plw = plb + w * 1280;

  // Q fragments: A[row=lr][k = ks*32 + lg*8 + j]
  bf16x8 qf[16];
  {
    const u16* qrow = bnn + (size_t)(r0 + lr) * DT;
#pragma unroll
    for (int ks = 0; ks < 16; ++ks)
      qf[ks] = *(const bf16x8*)(qrow + ks * 32 + lg * 8);
  }
  f32x4 acc[32];
#pragma unroll
  for (int i = 0; i < 32; ++i) acc[i] = (f32x4){0.f, 0.f, 0.f, 0.f};
  float m_s[4] = {-INFINITY, -INFINITY, -INFINITY, -INFINITY};
  float l_s[4] = {0.f, 0.f, 0.f, 0.f};

  for (int it = 0; it < NITER; ++it) {
    const int v0 = vbase + it * NT;
    // stage emb rows (row-major) -- source pre-swizzled so LDS dest is linear
#pragma unroll
    for (int i = 0; i < 8; ++i) {
      int v = w * 8 + i;
      void* src = (void*)((char*)(embB + (size_t)(v0 + v) * DT) + ((l ^ (v & 7)) << 4));
      gload16(src, ekb + v * 1024);
    }
    // stage embT rows (transposed tile)
#pragma unroll
    for (int i = 0; i < 8; ++i) {
      int chunk = w * 8 + i;
      int d = chunk * 16 + (l >> 2);
      int gs = (l & 3) ^ ((d ^ (d >> 2)) & 3);
      void* src = (void*)((char*)(embT + (size_t)d * NV + v0) + (gs << 4));
      gload16(src, evb + chunk * 1024);
    }
    float inq0 = invn[v0 + lr];
    float inq1 = invn[v0 + 16 + lr];
    __syncthreads();  // drains vmcnt -> staged tiles visible

    // QK^T : S[16 rows x 32 vocab] as two 16x16 tiles
    f32x4 s0 = {0.f, 0.f, 0.f, 0.f}, s1 = {0.f, 0.f, 0.f, 0.f};
#pragma unroll
    for (int ks = 0; ks < 16; ++ks) {
      const int c0 = lr, c1 = 16 + lr;
      bf16x8 b0 = *(const bf16x8*)(ekb + c0 * 1024 + ((((ks << 2) + lg) ^ (c0 & 7)) << 4));
      bf16x8 b1 = *(const bf16x8*)(ekb + c1 * 1024 + ((((ks << 2) + lg) ^ (c1 & 7)) << 4));
      s0 = __builtin_amdgcn_mfma_f32_16x16x32_bf16(qf[ks], b0, s0, 0, 0, 0);
      s1 = __builtin_amdgcn_mfma_f32_16x16x32_bf16(qf[ks], b1, s1, 0, 0, 0);
    }
    // online softmax: lane holds rows {4*lg+j}, vocab col lr(+16)
    float sa[4], sb[4], mx[4];
#pragma unroll
    for (int j = 0; j < 4; ++j) {
      sa[j] = s0[j] * inq0;
      sb[j] = s1[j] * inq1;
      mx[j] = fmaxf(sa[j], sb[j]);
    }
#pragma unroll
    for (int off = 1; off < 16; off <<= 1)
#pragma unroll
      for (int j = 0; j < 4; ++j) mx[j] = fmaxf(mx[j], __shfl_xor(mx[j], off));
    float need = fmaxf(fmaxf(mx[0] - m_s[0], mx[1] - m_s[1]),
                       fmaxf(mx[2] - m_s[2], mx[3] - m_s[3]));
    if (__any(need > 8.f)) {  // defer-max (T13)
      float cor[4];
#pragma unroll
      for (int j = 0; j < 4; ++j) {
        float mn = fmaxf(m_s[j], mx[j]);
        cor[j] = __expf(m_s[j] - mn);
        m_s[j] = mn; l_s[j] *= cor[j];
      }
#pragma unroll
      for (int dt = 0; dt < 32; ++dt) {
        acc[dt][0] *= cor[0]; acc[dt][1] *= cor[1];
        acc[dt][2] *= cor[2]; acc[dt][3] *= cor[3];
      }
    }
    float rs[4];
#pragma unroll
    for (int j = 0; j < 4; ++j) {
      sa[j] = __expf(sa[j] - m_s[j]);
      sb[j] = __expf(sb[j] - m_s[j]);
      rs[j] = sa[j] + sb[j];
    }
#pragma unroll
    for (int off = 1; off < 16; off <<= 1)
#pragma unroll
      for (int j = 0; j < 4; ++j) rs[j] += __shfl_xor(rs[j], off);
#pragma unroll
    for (int j = 0; j < 4; ++j) l_s[j] += rs[j];

    // P -> per-wave LDS bounce to A-fragment layout
#pragma unroll
    for (int j = 0; j < 4; ++j) {
      int row = (lg << 2) + j;
      *(u16*)(plw + row * 80 + lr * 2) = f2bf(sa[j]);
      *(u16*)(plw + row * 80 + (16 + lr) * 2) = f2bf(sb[j]);
    }
    asm volatile("s_waitcnt lgkmcnt(0)" ::: "memory");
    bf16x8 pa = *(const bf16x8*)(plw + lr * 80 + lg * 16);

    // PV: acc[16 x 512] += P[16 x 32] @ V[32 x 512]
#pragma unroll
    for (int dt = 0; dt < 32; ++dt) {
      int row = dt * 16 + lr;
      int g = lg ^ ((row ^ (row >> 2)) & 3);
      bf16x8 vb = *(const bf16x8*)(evb + row * 64 + (g << 4));
      acc[dt] = __builtin_amdgcn_mfma_f32_16x16x32_bf16(pa, vb, acc[dt], 0, 0, 0);
    }
    __syncthreads();  // all reads done before next stage overwrites tiles
  }

  // write partials
  float* po = pacc + ((size_t)vs * MROWS + r0) * DT;
#pragma unroll
  for (int dt = 0; dt < 32; ++dt)
#pragma unroll
    for (int j = 0; j < 4; ++j)
      po[(size_t)((lg << 2) + j) * DT + dt * 16 + lr] = acc[dt][j];
  if (lr == 0) {
#pragma unroll
    for (int j = 0; j < 4; ++j) {
      size_t row = (size_t)vs * MROWS + r0 + (lg << 2) + j;
      pml[row * 2 + 0] = m_s[j];
      pml[row * 2 + 1] = l_s[j];
    }
  }
}

// ---------------- combine split-vocab partials ---------------------------
__global__ __launch_bounds__(256) void k_combine(const float* __restrict__ pacc,
                                                 const float* __restrict__ pml,
                                                 float* __restrict__ out) {
  const int r = blockIdx.x;
  const int t = threadIdx.x;
  float m[VSPLIT], li[VSPLIT];
  float mM = -INFINITY;
#pragma unroll
  for (int i = 0; i < VSPLIT; ++i) {
    m[i] = pml[((size_t)i * MROWS + r) * 2 + 0];
    li[i] = pml[((size_t)i * MROWS + r) * 2 + 1];
    mM = fmaxf(mM, m[i]);
  }
  float L = 0.f, wgt[VSPLIT];
#pragma unroll
  for (int i = 0; i < VSPLIT; ++i) { wgt[i] = __expf(m[i] - mM); L += wgt[i] * li[i]; }
  float invL = 1.0f / L;
#pragma unroll
  for (int cc = 0; cc < 2; ++cc) {
    int c = t + cc * 256;
    float o = 0.f;
#pragma unroll
    for (int i = 0; i < VSPLIT; ++i)
      o += wgt[i] * pacc[((size_t)i * MROWS + r) * DT + c];
    out[(size_t)r * DT + c] = o * invL;
  }
}

extern "C" void kernel_launch(void* const* d_in, const int* in_sizes, int n_in,
                              void* d_out, int out_size, void* d_ws, size_t ws_size,
                              hipStream_t stream) {
  const float* audio = (const float*)d_in[0];
  const float* W     = (const float*)d_in[1];
  const float* bias  = (const float*)d_in[2];
  const float* gamma = (const float*)d_in[3];
  const float* beta  = (const float*)d_in[4];
  const float* emb   = (const float*)d_in[5];
  float* out = (float*)d_out;

  char* ws = (char*)d_ws;
  size_t off = 0;
  auto alloc = [&](size_t bytes) {
    char* p = ws + off;
    off += (bytes + 255) & ~(size_t)255;
    return p;
  };
  float* proj  = (float*)alloc((size_t)MROWS * DT * 4);
  float* pstat = (float*)alloc((size_t)64 * 1024 * 4);
  float* stats = (float*)alloc((size_t)2 * DT * 4);
  u16*   bnn   = (u16*)alloc((size_t)MROWS * DT * 2);
  u16*   embB  = (u16*)alloc((size_t)NV * DT * 2);
  u16*   embT  = (u16*)alloc((size_t)DT * NV * 2);
  float* invn  = (float*)alloc((size_t)NV * 4);
  float* pml   = (float*)alloc((size_t)VSPLIT * MROWS * 2 * 4);
  float* pacc  = (float*)alloc((size_t)VSPLIT * MROWS * DT * 4);
  if (ws_size < off) return;  // scratch too small -> visible as validation failure

  k_proj<<<dim3(32, 8), dim3(256), 0, stream>>>(audio, W, bias, proj);
  k_stats<<<dim3(64), dim3(256), 0, stream>>>(proj, pstat);
  k_stats2<<<dim3(4), dim3(256), 0, stream>>>(pstat, stats);
  k_bnnorm<<<dim3(MROWS), dim3(64), 0, stream>>>(proj, stats, gamma, beta, bnn);
  k_embprep<<<dim3(NV / 4), dim3(256), 0, stream>>>(emb, embB, invn);
  k_embT<<<dim3(NV / 64, DT / 64), dim3(256), 0, stream>>>(emb, embT);

  const int shbytes = 32768 + 32768 + 4 * 16 * 80;  // 70656
  hipFuncSetAttribute((const void*)k_flash,
                      hipFuncAttributeMaxDynamicSharedMemorySize, shbytes);
  k_flash<<<dim3(32, VSPLIT), dim3(256), shbytes, stream>>>(bnn, embB, embT, invn,
                                                            pacc, pml);
  k_combine<<<dim3(MROWS), dim3(256), 0, stream>>>(pacc, pml, out);
}

// Round 2
// 578.756 us; speedup vs baseline: 1.1350x; 1.1350x over previous
//
#include <hip/hip_runtime.h>
#include <stdint.h>

typedef unsigned short u16;
typedef _Float16 f16;
typedef __attribute__((ext_vector_type(8))) _Float16 f16x8;
typedef __attribute__((ext_vector_type(4))) float f32x4;

#define DA 768
#define DT 512
#define NV 49408
#define MTOT 2048
#define NB_N 386        // NV / 128
#define KSPLIT 8
#define KSL (NV / KSPLIT)   // 6176 = 193 * 32

__device__ __forceinline__ u16 f2h(float f) {
  return __builtin_bit_cast(u16, (f16)f);
}

__device__ __forceinline__ void gload16(const void* g, void* l) {
  __builtin_amdgcn_global_load_lds((const __attribute__((address_space(1))) void*)g,
                                   (__attribute__((address_space(3))) void*)l,
                                   16, 0, 0);
}

// ---------------- proj = audio @ W + b (fp32, 64x64 tile) ----------------
__global__ __launch_bounds__(256) void k_proj(const float* __restrict__ A,
                                              const float* __restrict__ W,
                                              const float* __restrict__ bias,
                                              float* __restrict__ P) {
  __shared__ float As[16][72];
  __shared__ float Bs[16][72];
  const int m0 = blockIdx.x * 64, n0 = blockIdx.y * 64;
  const int t = threadIdx.x;
  const int ty = t >> 4, tx = t & 15;
  const int ar = t >> 2, ak = (t & 3) * 4;
  const int bk = t >> 4, bn = (t & 15) * 4;
  float acc[4][4] = {};
  for (int k0 = 0; k0 < DA; k0 += 16) {
    float4 av = *(const float4*)&A[(size_t)(m0 + ar) * DA + k0 + ak];
    float4 bv = *(const float4*)&W[(size_t)(k0 + bk) * DT + n0 + bn];
    __syncthreads();
    As[ak + 0][ar] = av.x; As[ak + 1][ar] = av.y;
    As[ak + 2][ar] = av.z; As[ak + 3][ar] = av.w;
    *(float4*)&Bs[bk][bn] = bv;
    __syncthreads();
#pragma unroll
    for (int kk = 0; kk < 16; ++kk) {
      float4 a4 = *(const float4*)&As[kk][ty * 4];
      float4 b4 = *(const float4*)&Bs[kk][tx * 4];
      float ae[4] = {a4.x, a4.y, a4.z, a4.w};
      float be[4] = {b4.x, b4.y, b4.z, b4.w};
#pragma unroll
      for (int i = 0; i < 4; ++i)
#pragma unroll
        for (int j = 0; j < 4; ++j) acc[i][j] = fmaf(ae[i], be[j], acc[i][j]);
    }
  }
#pragma unroll
  for (int i = 0; i < 4; ++i) {
    int row = m0 + ty * 4 + i;
    float4 o;
    o.x = acc[i][0] + bias[n0 + tx * 4 + 0];
    o.y = acc[i][1] + bias[n0 + tx * 4 + 1];
    o.z = acc[i][2] + bias[n0 + tx * 4 + 2];
    o.w = acc[i][3] + bias[n0 + tx * 4 + 3];
    *(float4*)&P[(size_t)row * DT + n0 + tx * 4] = o;
  }
}

// ---------------- BN stats: partial sums (deterministic) -----------------
__global__ __launch_bounds__(256) void k_stats(const float* __restrict__ P,
                                               float* __restrict__ pstat) {
  const int t = threadIdx.x;
  const int r0 = blockIdx.x * 32;
  float s0 = 0, q0 = 0, s1 = 0, q1 = 0;
  for (int r = r0; r < r0 + 32; ++r) {
    float x0 = P[(size_t)r * DT + t];
    float x1 = P[(size_t)r * DT + t + 256];
    s0 += x0; q0 += x0 * x0; s1 += x1; q1 += x1 * x1;
  }
  float* d = pstat + (size_t)blockIdx.x * 1024;
  d[t] = s0; d[t + 256] = s1; d[512 + t] = q0; d[768 + t] = q1;
}

__global__ __launch_bounds__(256) void k_stats2(const float* __restrict__ pstat,
                                                float* __restrict__ stats) {
  int c = blockIdx.x * 256 + threadIdx.x;  // 0..1023
  float s = 0.f;
  for (int b = 0; b < 64; ++b) s += pstat[(size_t)b * 1024 + c];
  stats[c] = s;
}

// ---------------- BN apply + row L2 normalize -> bnnH (f16) --------------
__global__ __launch_bounds__(64) void k_bnnorm(const float* __restrict__ P,
                                               const float* __restrict__ stats,
                                               const float* __restrict__ gamma,
                                               const float* __restrict__ beta,
                                               u16* __restrict__ bnn) {
  const int r = blockIdx.x, l = threadIdx.x;
  float v[8];
  float ss = 0.f;
#pragma unroll
  for (int i = 0; i < 8; ++i) {
    int c = l * 8 + i;
    float mean = stats[c] * (1.f / MTOT);
    float var = stats[DT + c] * (1.f / MTOT) - mean * mean;
    float is = rsqrtf(var + 1e-5f);
    float x = (P[(size_t)r * DT + c] - mean) * is * gamma[c] + beta[c];
    v[i] = x; ss += x * x;
  }
#pragma unroll
  for (int off = 32; off > 0; off >>= 1) ss += __shfl_xor(ss, off);
  float rn = rsqrtf(ss);
  union { u16 u[8]; int4 q; } pk;
#pragma unroll
  for (int i = 0; i < 8; ++i) pk.u[i] = f2h(v[i] * rn);
  *(int4*)&bnn[(size_t)r * DT + l * 8] = pk.q;
}

// ---------------- emb -> f16 rows + 10/||emb|| ---------------------------
__global__ __launch_bounds__(256) void k_embprep(const float* __restrict__ emb,
                                                 u16* __restrict__ embH,
                                                 float* __restrict__ invn) {
  const int w = threadIdx.x >> 6, l = threadIdx.x & 63;
  const int vrow = blockIdx.x * 4 + w;
  const float* src = emb + (size_t)vrow * DT + l * 8;
  float4 a = *(const float4*)src;
  float4 b = *(const float4*)(src + 4);
  float x[8] = {a.x, a.y, a.z, a.w, b.x, b.y, b.z, b.w};
  float ss = 0.f;
#pragma unroll
  for (int i = 0; i < 8; ++i) ss += x[i] * x[i];
#pragma unroll
  for (int off = 32; off > 0; off >>= 1) ss += __shfl_xor(ss, off);
  if (l == 0) invn[vrow] = rsqrtf(ss) * 10.0f;  // (1/||emb_v||) * (1/T)
  union { u16 u[8]; int4 q; } pk;
#pragma unroll
  for (int i = 0; i < 8; ++i) pk.u[i] = f2h(x[i]);
  *(int4*)&embH[(size_t)vrow * DT + l * 8] = pk.q;
}

// ---------------- embT[d][v] = f16(emb[v][d]) ----------------------------
__global__ __launch_bounds__(256) void k_embT(const float* __restrict__ emb,
                                              u16* __restrict__ embT) {
  __shared__ float tile[64][65];
  const int v0 = blockIdx.x * 64, d0 = blockIdx.y * 64;
  const int t = threadIdx.x;
  {
    const int r = t >> 4, c = (t & 15) * 4;
#pragma unroll
    for (int i = 0; i < 4; ++i) {
      float4 x = *(const float4*)&emb[(size_t)(v0 + r + i * 16) * DT + d0 + c];
      tile[r + i * 16][c + 0] = x.x; tile[r + i * 16][c + 1] = x.y;
      tile[r + i * 16][c + 2] = x.z; tile[r + i * 16][c + 3] = x.w;
    }
  }
  __syncthreads();
  {
    const int d = t >> 2;
    const int vc = (t & 3) * 16;
    union { u16 u[8]; int4 q; } p0, p1;
#pragma unroll
    for (int i = 0; i < 8; ++i) p0.u[i] = f2h(tile[vc + i][d]);
#pragma unroll
    for (int i = 0; i < 8; ++i) p1.u[i] = f2h(tile[vc + 8 + i][d]);
    u16* dst = embT + (size_t)(d0 + d) * NV + v0 + vc;
    *(int4*)dst = p0.q;
    *(int4*)(dst + 8) = p1.q;
  }
}

// ---------------- k_score: E = exp(invn * (bnnH @ embH^T)) + row psums ---
// m97-pattern 128x128x32 GEMM, 4 waves of 64x64.
__global__ __launch_bounds__(256) void k_score(const f16* __restrict__ A,   // bnnH [2048][512]
                                               const f16* __restrict__ Bt,  // embH [NV][512]
                                               const float* __restrict__ invn,
                                               u16* __restrict__ E,         // [CH][NV] f16
                                               float* __restrict__ lpart,   // [NB_N][CH]
                                               int row0, int CH) {
  __shared__ f16 As[128 * 32];
  __shared__ f16 Bs[128 * 32];
  const int t = threadIdx.x;
  const int w = t >> 6, l = t & 63;
  const int lr = l & 15, lg = l >> 4;
  const int wr = w >> 1, wc = w & 1;
  const int nb = blockIdx.x, by = blockIdx.y;
  const int n0 = nb * 128;
  const int m0 = row0 + by * 128;

  const int c1 = t, c2 = t + 256;
  const int r1 = c1 >> 2, q1 = c1 & 3;
  const int r2 = c2 >> 2, q2 = c2 & 3;
  const int qs1 = q1 ^ ((r1 >> 1) & 3);   // pre-swizzled global quarter (rule #21)
  const int qs2 = q2 ^ ((r2 >> 1) & 3);
  const f16* ga1 = A + (size_t)(m0 + r1) * DT + qs1 * 8;
  const f16* ga2 = A + (size_t)(m0 + r2) * DT + qs2 * 8;
  const f16* gb1 = Bt + (size_t)(n0 + r1) * DT + qs1 * 8;
  const f16* gb2 = Bt + (size_t)(n0 + r2) * DT + qs2 * 8;
  const int gsw = lg ^ ((lr >> 1) & 3);   // matching read-granule swizzle

  f32x4 acc[4][4];
#pragma unroll
  for (int i = 0; i < 4; ++i)
#pragma unroll
    for (int j = 0; j < 4; ++j) acc[i][j] = (f32x4){0.f, 0.f, 0.f, 0.f};

  for (int k0 = 0; k0 < DT; k0 += 32) {
    gload16(ga1 + k0, &As[c1 * 8]);
    gload16(ga2 + k0, &As[c2 * 8]);
    gload16(gb1 + k0, &Bs[c1 * 8]);
    gload16(gb2 + k0, &Bs[c2 * 8]);
    __syncthreads();
    f16x8 af[4], bf[4];
#pragma unroll
    for (int i = 0; i < 4; ++i)
      af[i] = *(const f16x8*)&As[(wr * 64 + i * 16 + lr) * 32 + gsw * 8];
#pragma unroll
    for (int j = 0; j < 4; ++j)
      bf[j] = *(const f16x8*)&Bs[(wc * 64 + j * 16 + lr) * 32 + gsw * 8];
#pragma unroll
    for (int i = 0; i < 4; ++i)
#pragma unroll
      for (int j = 0; j < 4; ++j)
        acc[i][j] = __builtin_amdgcn_mfma_f32_16x16x32_f16(af[i], bf[j], acc[i][j], 0, 0, 0);
    __syncthreads();
  }

  // epilogue: exp, store E (f16), per-row partial sums
  float inv_j[4];
#pragma unroll
  for (int j = 0; j < 4; ++j) inv_j[j] = invn[n0 + wc * 64 + j * 16 + lr];
  float rs[4][4] = {};
#pragma unroll
  for (int i = 0; i < 4; ++i) {
#pragma unroll
    for (int j = 0; j < 4; ++j) {
#pragma unroll
      for (int rg = 0; rg < 4; ++rg) {
        float e = __expf(acc[i][j][rg] * inv_j[j]);
        rs[i][rg] += e;
        int erow = by * 128 + wr * 64 + i * 16 + lg * 4 + rg;
        int n = n0 + wc * 64 + j * 16 + lr;
        E[(size_t)erow * NV + n] = f2h(e);
      }
    }
  }
#pragma unroll
  for (int m = 1; m <= 8; m <<= 1)
#pragma unroll
    for (int i = 0; i < 4; ++i)
#pragma unroll
      for (int rg = 0; rg < 4; ++rg) rs[i][rg] += __shfl_xor(rs[i][rg], m);
  float* ps = (float*)As;  // reuse (all frag reads completed at loop-end barrier)
  if (lr == 0) {
#pragma unroll
    for (int i = 0; i < 4; ++i)
#pragma unroll
      for (int rg = 0; rg < 4; ++rg)
        ps[w * 64 + i * 16 + lg * 4 + rg] = rs[i][rg];
  }
  __syncthreads();
  if (t < 128) {
    float v = (t < 64) ? (ps[t] + ps[64 + t]) : (ps[128 + (t - 64)] + ps[192 + (t - 64)]);
    lpart[(size_t)nb * CH + by * 128 + t] = v;
  }
}

// ---------------- k_pv: Opart[z] = E @ embT^T (split-K) ------------------
__global__ __launch_bounds__(256) void k_pv(const f16* __restrict__ A,   // E [CH][NV]
                                            const f16* __restrict__ Bt,  // embT [512][NV]
                                            float* __restrict__ Op,      // [KSPLIT][CH][512]
                                            int CH) {
  __shared__ f16 As[128 * 32];
  __shared__ f16 Bs[128 * 32];
  const int t = threadIdx.x;
  const int w = t >> 6, l = t & 63;
  const int lr = l & 15, lg = l >> 4;
  const int wr = w >> 1, wc = w & 1;
  const int n0 = blockIdx.x * 128;
  const int m0 = blockIdx.y * 128;
  const int bz = blockIdx.z;
  const size_t kb = (size_t)bz * KSL;

  const int c1 = t, c2 = t + 256;
  const int r1 = c1 >> 2, q1 = c1 & 3;
  const int r2 = c2 >> 2, q2 = c2 & 3;
  const int qs1 = q1 ^ ((r1 >> 1) & 3);
  const int qs2 = q2 ^ ((r2 >> 1) & 3);
  const f16* ga1 = A + (size_t)(m0 + r1) * NV + kb + qs1 * 8;
  const f16* ga2 = A + (size_t)(m0 + r2) * NV + kb + qs2 * 8;
  const f16* gb1 = Bt + (size_t)(n0 + r1) * NV + kb + qs1 * 8;
  const f16* gb2 = Bt + (size_t)(n0 + r2) * NV + kb + qs2 * 8;
  const int gsw = lg ^ ((lr >> 1) & 3);

  f32x4 acc[4][4];
#pragma unroll
  for (int i = 0; i < 4; ++i)
#pragma unroll
    for (int j = 0; j < 4; ++j) acc[i][j] = (f32x4){0.f, 0.f, 0.f, 0.f};

  for (int k0 = 0; k0 < KSL; k0 += 32) {
    gload16(ga1 + k0, &As[c1 * 8]);
    gload16(ga2 + k0, &As[c2 * 8]);
    gload16(gb1 + k0, &Bs[c1 * 8]);
    gload16(gb2 + k0, &Bs[c2 * 8]);
    __syncthreads();
    f16x8 af[4], bf[4];
#pragma unroll
    for (int i = 0; i < 4; ++i)
      af[i] = *(const f16x8*)&As[(wr * 64 + i * 16 + lr) * 32 + gsw * 8];
#pragma unroll
    for (int j = 0; j < 4; ++j)
      bf[j] = *(const f16x8*)&Bs[(wc * 64 + j * 16 + lr) * 32 + gsw * 8];
#pragma unroll
    for (int i = 0; i < 4; ++i)
#pragma unroll
      for (int j = 0; j < 4; ++j)
        acc[i][j] = __builtin_amdgcn_mfma_f32_16x16x32_f16(af[i], bf[j], acc[i][j], 0, 0, 0);
    __syncthreads();
  }
#pragma unroll
  for (int i = 0; i < 4; ++i)
#pragma unroll
    for (int j = 0; j < 4; ++j)
#pragma unroll
      for (int rg = 0; rg < 4; ++rg) {
        int row = m0 + wr * 64 + i * 16 + lg * 4 + rg;
        int col = n0 + wc * 64 + j * 16 + lr;
        Op[((size_t)bz * CH + row) * DT + col] = acc[i][j][rg];
      }
}

// ---------------- l[r] = sum over vocab of E -----------------------------
__global__ __launch_bounds__(256) void k_lred(const float* __restrict__ lp,
                                              float* __restrict__ lv, int CH) {
  int rb = blockIdx.x * 256 + threadIdx.x;
  float s = 0.f;
  for (int nb = 0; nb < NB_N; ++nb) s += lp[(size_t)nb * CH + rb];
  lv[rb] = s;
}

// ---------------- combine split-K + divide by l --------------------------
__global__ __launch_bounds__(256) void k_out(const float* __restrict__ Op,
                                             const float* __restrict__ lv,
                                             float* __restrict__ out,
                                             int row0, int CH) {
  int idx = blockIdx.x * 256 + threadIdx.x;
  int rb = idx >> 9, c = idx & 511;
  float s = 0.f;
#pragma unroll
  for (int z = 0; z < KSPLIT; ++z) s += Op[((size_t)z * CH + rb) * DT + c];
  out[(size_t)(row0 + rb) * DT + c] = s / lv[rb];
}

extern "C" void kernel_launch(void* const* d_in, const int* in_sizes, int n_in,
                              void* d_out, int out_size, void* d_ws, size_t ws_size,
                              hipStream_t stream) {
  const float* audio = (const float*)d_in[0];
  const float* W     = (const float*)d_in[1];
  const float* bias  = (const float*)d_in[2];
  const float* gamma = (const float*)d_in[3];
  const float* beta  = (const float*)d_in[4];
  const float* emb   = (const float*)d_in[5];
  float* out = (float*)d_out;

  char* ws = (char*)d_ws;
  size_t off = 0;
  auto alloc = [&](size_t bytes) {
    char* p = ws + off;
    off += (bytes + 255) & ~(size_t)255;
    return p;
  };
  float* proj  = (float*)alloc((size_t)MTOT * DT * 4);
  float* pstat = (float*)alloc((size_t)64 * 1024 * 4);
  float* stats = (float*)alloc((size_t)2 * DT * 4);
  u16*   bnnH  = (u16*)alloc((size_t)MTOT * DT * 2);
  u16*   embH  = (u16*)alloc((size_t)NV * DT * 2);
  u16*   embT  = (u16*)alloc((size_t)DT * NV * 2);
  float* invn  = (float*)alloc((size_t)NV * 4);
  size_t fixed_off = off;

  // pick the largest row-chunk that fits the workspace
  int CH = 2048;
  while (CH > 256) {
    size_t need = fixed_off;
    need += (((size_t)CH * NV * 2) + 255 & ~(size_t)255);        // E
    need += (((size_t)NB_N * CH * 4) + 255 & ~(size_t)255);      // lpart
    need += (((size_t)CH * 4) + 255 & ~(size_t)255);             // l
    need += (((size_t)KSPLIT * CH * DT * 4) + 255 & ~(size_t)255); // Opart
    if (need <= ws_size) break;
    CH >>= 1;
  }
  u16*   E     = (u16*)alloc((size_t)CH * NV * 2);
  float* lpart = (float*)alloc((size_t)NB_N * CH * 4);
  float* lvec  = (float*)alloc((size_t)CH * 4);
  float* Op    = (float*)alloc((size_t)KSPLIT * CH * DT * 4);
  if (ws_size < off) return;  // visible as validation failure

  k_proj<<<dim3(32, 8), dim3(256), 0, stream>>>(audio, W, bias, proj);
  k_stats<<<dim3(64), dim3(256), 0, stream>>>(proj, pstat);
  k_stats2<<<dim3(4), dim3(256), 0, stream>>>(pstat, stats);
  k_bnnorm<<<dim3(MTOT), dim3(64), 0, stream>>>(proj, stats, gamma, beta, bnnH);
  k_embprep<<<dim3(NV / 4), dim3(256), 0, stream>>>(emb, embH, invn);
  k_embT<<<dim3(NV / 64, DT / 64), dim3(256), 0, stream>>>(emb, embT);

  for (int row0 = 0; row0 < MTOT; row0 += CH) {
    k_score<<<dim3(NB_N, CH / 128), dim3(256), 0, stream>>>(
        (const f16*)bnnH, (const f16*)embH, invn, E, lpart, row0, CH);
    k_lred<<<dim3(CH / 256), dim3(256), 0, stream>>>(lpart, lvec, CH);
    k_pv<<<dim3(4, CH / 128, KSPLIT), dim3(256), 0, stream>>>(
        (const f16*)E, (const f16*)embT, Op, CH);
    k_out<<<dim3(CH * 2), dim3(256), 0, stream>>>(Op, lvec, out, row0, CH);
  }
}

// Round 3
// 442.599 us; speedup vs baseline: 1.4842x; 1.3076x over previous
//
#include <hip/hip_runtime.h>
#include <stdint.h>

typedef unsigned short u16;
typedef _Float16 f16;
typedef __attribute__((ext_vector_type(8))) _Float16 f16x8;
typedef __attribute__((ext_vector_type(4))) float f32x4;

#define DA 768
#define DT 512
#define NV 49408
#define MTOT 2048
#define NB_N 193          // n-blocks for k_score (256-wide tiles)
#define KS 16             // k_pv K-split

__device__ __forceinline__ u16 f2h(float f) {
  return __builtin_bit_cast(u16, (f16)f);
}

__device__ __forceinline__ void gload16(const void* g, void* l) {
  __builtin_amdgcn_global_load_lds((const __attribute__((address_space(1))) void*)g,
                                   (__attribute__((address_space(3))) void*)l,
                                   16, 0, 0);
}
#define SBAR()   __builtin_amdgcn_s_barrier()
#define SCHED0() __builtin_amdgcn_sched_barrier(0)

// ---------------- proj = audio @ W + b (fp32, 64x64 tile) ----------------
__global__ __launch_bounds__(256) void k_proj(const float* __restrict__ A,
                                              const float* __restrict__ W,
                                              const float* __restrict__ bias,
                                              float* __restrict__ P) {
  __shared__ float As[16][72];
  __shared__ float Bs[16][72];
  const int m0 = blockIdx.x * 64, n0 = blockIdx.y * 64;
  const int t = threadIdx.x;
  const int ty = t >> 4, tx = t & 15;
  const int ar = t >> 2, ak = (t & 3) * 4;
  const int bk = t >> 4, bn = (t & 15) * 4;
  float acc[4][4] = {};
  for (int k0 = 0; k0 < DA; k0 += 16) {
    float4 av = *(const float4*)&A[(size_t)(m0 + ar) * DA + k0 + ak];
    float4 bv = *(const float4*)&W[(size_t)(k0 + bk) * DT + n0 + bn];
    __syncthreads();
    As[ak + 0][ar] = av.x; As[ak + 1][ar] = av.y;
    As[ak + 2][ar] = av.z; As[ak + 3][ar] = av.w;
    *(float4*)&Bs[bk][bn] = bv;
    __syncthreads();
#pragma unroll
    for (int kk = 0; kk < 16; ++kk) {
      float4 a4 = *(const float4*)&As[kk][ty * 4];
      float4 b4 = *(const float4*)&Bs[kk][tx * 4];
      float ae[4] = {a4.x, a4.y, a4.z, a4.w};
      float be[4] = {b4.x, b4.y, b4.z, b4.w};
#pragma unroll
      for (int i = 0; i < 4; ++i)
#pragma unroll
        for (int j = 0; j < 4; ++j) acc[i][j] = fmaf(ae[i], be[j], acc[i][j]);
    }
  }
#pragma unroll
  for (int i = 0; i < 4; ++i) {
    int row = m0 + ty * 4 + i;
    float4 o;
    o.x = acc[i][0] + bias[n0 + tx * 4 + 0];
    o.y = acc[i][1] + bias[n0 + tx * 4 + 1];
    o.z = acc[i][2] + bias[n0 + tx * 4 + 2];
    o.w = acc[i][3] + bias[n0 + tx * 4 + 3];
    *(float4*)&P[(size_t)row * DT + n0 + tx * 4] = o;
  }
}

// ---------------- BN stats ----------------------------------------------
__global__ __launch_bounds__(256) void k_stats(const float* __restrict__ P,
                                               float* __restrict__ pstat) {
  const int t = threadIdx.x;
  const int r0 = blockIdx.x * 32;
  float s0 = 0, q0 = 0, s1 = 0, q1 = 0;
  for (int r = r0; r < r0 + 32; ++r) {
    float x0 = P[(size_t)r * DT + t];
    float x1 = P[(size_t)r * DT + t + 256];
    s0 += x0; q0 += x0 * x0; s1 += x1; q1 += x1 * x1;
  }
  float* d = pstat + (size_t)blockIdx.x * 1024;
  d[t] = s0; d[t + 256] = s1; d[512 + t] = q0; d[768 + t] = q1;
}

__global__ __launch_bounds__(256) void k_stats2(const float* __restrict__ pstat,
                                                float* __restrict__ stats) {
  int c = blockIdx.x * 256 + threadIdx.x;
  float s = 0.f;
  for (int b = 0; b < 64; ++b) s += pstat[(size_t)b * 1024 + c];
  stats[c] = s;
}

// ---------------- BN apply + row L2 normalize -> f16 ---------------------
__global__ __launch_bounds__(64) void k_bnnorm(const float* __restrict__ P,
                                               const float* __restrict__ stats,
                                               const float* __restrict__ gamma,
                                               const float* __restrict__ beta,
                                               u16* __restrict__ bnn) {
  const int r = blockIdx.x, l = threadIdx.x;
  float v[8];
  float ss = 0.f;
#pragma unroll
  for (int i = 0; i < 8; ++i) {
    int c = l * 8 + i;
    float mean = stats[c] * (1.f / MTOT);
    float var = stats[DT + c] * (1.f / MTOT) - mean * mean;
    float is = rsqrtf(var + 1e-5f);
    float x = (P[(size_t)r * DT + c] - mean) * is * gamma[c] + beta[c];
    v[i] = x; ss += x * x;
  }
#pragma unroll
  for (int off = 32; off > 0; off >>= 1) ss += __shfl_xor(ss, off);
  float rn = rsqrtf(ss);
  union { u16 u[8]; int4 q; } pk;
#pragma unroll
  for (int i = 0; i < 8; ++i) pk.u[i] = f2h(v[i] * rn);
  *(int4*)&bnn[(size_t)r * DT + l * 8] = pk.q;
}

// ---------------- emb -> f16 rows + 10/||emb|| ---------------------------
__global__ __launch_bounds__(256) void k_embprep(const float* __restrict__ emb,
                                                 u16* __restrict__ embH,
                                                 float* __restrict__ invn) {
  const int w = threadIdx.x >> 6, l = threadIdx.x & 63;
  const int vrow = blockIdx.x * 4 + w;
  const float* src = emb + (size_t)vrow * DT + l * 8;
  float4 a = *(const float4*)src;
  float4 b = *(const float4*)(src + 4);
  float x[8] = {a.x, a.y, a.z, a.w, b.x, b.y, b.z, b.w};
  float ss = 0.f;
#pragma unroll
  for (int i = 0; i < 8; ++i) ss += x[i] * x[i];
#pragma unroll
  for (int off = 32; off > 0; off >>= 1) ss += __shfl_xor(ss, off);
  if (l == 0) invn[vrow] = rsqrtf(ss) * 10.0f;
  union { u16 u[8]; int4 q; } pk;
#pragma unroll
  for (int i = 0; i < 8; ++i) pk.u[i] = f2h(x[i]);
  *(int4*)&embH[(size_t)vrow * DT + l * 8] = pk.q;
}

// ---------------- embT[d][v] = f16(emb[v][d]) ----------------------------
__global__ __launch_bounds__(256) void k_embT(const float* __restrict__ emb,
                                              u16* __restrict__ embT) {
  __shared__ float tile[64][65];
  const int v0 = blockIdx.x * 64, d0 = blockIdx.y * 64;
  const int t = threadIdx.x;
  {
    const int r = t >> 4, c = (t & 15) * 4;
#pragma unroll
    for (int i = 0; i < 4; ++i) {
      float4 x = *(const float4*)&emb[(size_t)(v0 + r + i * 16) * DT + d0 + c];
      tile[r + i * 16][c + 0] = x.x; tile[r + i * 16][c + 1] = x.y;
      tile[r + i * 16][c + 2] = x.z; tile[r + i * 16][c + 3] = x.w;
    }
  }
  __syncthreads();
  {
    const int d = t >> 2;
    const int vc = (t & 3) * 16;
    union { u16 u[8]; int4 q; } p0, p1;
#pragma unroll
    for (int i = 0; i < 8; ++i) p0.u[i] = f2h(tile[vc + i][d]);
#pragma unroll
    for (int i = 0; i < 8; ++i) p1.u[i] = f2h(tile[vc + 8 + i][d]);
    u16* dst = embT + (size_t)(d0 + d) * NV + v0 + vc;
    *(int4*)dst = p0.q;
    *(int4*)(dst + 8) = p1.q;
  }
}

// ======== pipelined 128x256 GEMM kernels (2-deep counted-vmcnt) ==========
// LDS per buffer: A 128x32 f16 (4096) + B 256x32 f16 (8192) = 12288 f16.

// ---------------- k_score: E = exp(invn * (bnnH @ embH^T)) ---------------
__global__ __launch_bounds__(256, 2) void k_score(const f16* __restrict__ A,
                                                  const f16* __restrict__ Bt,
                                                  const float* __restrict__ invn,
                                                  u16* __restrict__ E,
                                                  float* __restrict__ lpart,
                                                  int row0, int CH) {
  __shared__ f16 sm[2][12288];
  __shared__ float ps[256];
  const int t = threadIdx.x;
  const int w = t >> 6, l = t & 63;
  const int lr = l & 15, lg = l >> 4;
  const int wr = w >> 1, wc = w & 1;
  const int mB = CH >> 7;
  const int nwg = NB_N * mB;
  const int o = blockIdx.x + blockIdx.y * NB_N;      // x fastest (hw linear order)
  const int v = (o & 7) * (nwg >> 3) + (o >> 3);     // bijective XCD chunking
  const int nb = v / mB, by = v % mB;
  const int n0 = nb * 256;
  const int m0 = row0 + by * 128;

  // staging source pointers (pre-swizzled granule, rule #21)
  const int rA1 = t >> 2, qA1 = t & 3;
  const int rA2 = (t + 256) >> 2, qA2 = t & 3;  // (t+256)&3 == t&3
  const int qsA1 = qA1 ^ ((rA1 >> 1) & 3);
  const int qsA2 = qA2 ^ ((rA2 >> 1) & 3);
  const f16* gA1 = A + (size_t)(m0 + rA1) * DT + qsA1 * 8;
  const f16* gA2 = A + (size_t)(m0 + rA2) * DT + qsA2 * 8;
  const f16* gB[4];
#pragma unroll
  for (int s = 0; s < 4; ++s) {
    int c = t + 256 * s;
    int r = c >> 2, q = c & 3;
    int qs = q ^ ((r >> 1) & 3);
    gB[s] = Bt + (size_t)(n0 + r) * DT + qs * 8;
  }
  auto STAGE = [&](int buf, int k0) {
    gload16(gA1 + k0, (void*)&sm[buf][(size_t)t * 8]);
    gload16(gA2 + k0, (void*)&sm[buf][(size_t)(t + 256) * 8]);
    gload16(gB[0] + k0, (void*)&sm[buf][4096 + (size_t)t * 8]);
    gload16(gB[1] + k0, (void*)&sm[buf][4096 + (size_t)(t + 256) * 8]);
    gload16(gB[2] + k0, (void*)&sm[buf][4096 + (size_t)(t + 512) * 8]);
    gload16(gB[3] + k0, (void*)&sm[buf][4096 + (size_t)(t + 768) * 8]);
  };
  const int gsw = lg ^ ((lr >> 1) & 3);

  f32x4 acc[4][8];
#pragma unroll
  for (int i = 0; i < 4; ++i)
#pragma unroll
    for (int j = 0; j < 8; ++j) acc[i][j] = (f32x4){0.f, 0.f, 0.f, 0.f};

  STAGE(0, 0);
  STAGE(1, 32);
  asm volatile("s_waitcnt vmcnt(6)" ::: "memory"); SCHED0();
  SBAR(); SCHED0();
  int cur = 0;
  const int nit = DT / 32;  // 16
  for (int it = 0; it < nit; ++it) {
    const f16* bufA = sm[cur];
    const f16* bufB = sm[cur] + 4096;
    f16x8 af[4], bf[8];
#pragma unroll
    for (int i = 0; i < 4; ++i)
      af[i] = *(const f16x8*)&bufA[(wr * 64 + i * 16 + lr) * 32 + gsw * 8];
#pragma unroll
    for (int j = 0; j < 8; ++j)
      bf[j] = *(const f16x8*)&bufB[(wc * 128 + j * 16 + lr) * 32 + gsw * 8];
#pragma unroll
    for (int i = 0; i < 4; ++i)
#pragma unroll
      for (int j = 0; j < 8; ++j)
        acc[i][j] = __builtin_amdgcn_mfma_f32_16x16x32_f16(af[i], bf[j], acc[i][j], 0, 0, 0);
    asm volatile("s_waitcnt lgkmcnt(0)" ::: "memory"); SCHED0();
    SBAR(); SCHED0();
    if (it + 2 < nit) {
      STAGE(cur, (it + 2) * 32);
      asm volatile("s_waitcnt vmcnt(6)" ::: "memory");
    } else {
      asm volatile("s_waitcnt vmcnt(0)" ::: "memory");
    }
    SCHED0();
    SBAR(); SCHED0();
    cur ^= 1;
  }

  // ---- epilogue: exp -> E via LDS bounce (coalesced), row partial sums --
  float inv_j[8];
#pragma unroll
  for (int j = 0; j < 8; ++j) inv_j[j] = invn[n0 + wc * 128 + j * 16 + lr];
  float rs[4][4] = {};
  f16* bounce = &sm[0][0];  // 16384 f16 = [64 rows][256 cols]
#pragma unroll
  for (int r2 = 0; r2 < 2; ++r2) {
#pragma unroll
    for (int ii = 0; ii < 2; ++ii) {
      int i = r2 * 2 + ii;
#pragma unroll
      for (int j = 0; j < 8; ++j) {
#pragma unroll
        for (int rg = 0; rg < 4; ++rg) {
          float e = __expf(acc[i][j][rg] * inv_j[j]);
          rs[i][rg] += e;
          int s = wr * 32 + ii * 16 + lg * 4 + rg;
          bounce[s * 256 + wc * 128 + j * 16 + lr] = (f16)e;
        }
      }
    }
    __syncthreads();
#pragma unroll
    for (int cc = 0; cc < 8; ++cc) {
      int chunk = t + cc * 256;
      int s = chunk >> 5, off = chunk & 31;
      int grow = by * 128 + r2 * 32 + (s & 31) + (s >> 5) * 64;
      *(int4*)&E[(size_t)grow * NV + n0 + off * 8] = *(const int4*)&bounce[chunk * 8];
    }
    __syncthreads();
  }
#pragma unroll
  for (int m = 1; m <= 8; m <<= 1)
#pragma unroll
    for (int i = 0; i < 4; ++i)
#pragma unroll
      for (int rg = 0; rg < 4; ++rg) rs[i][rg] += __shfl_xor(rs[i][rg], m);
  if (lr == 0) {
#pragma unroll
    for (int i = 0; i < 4; ++i)
#pragma unroll
      for (int rg = 0; rg < 4; ++rg)
        ps[wc * 128 + wr * 64 + i * 16 + lg * 4 + rg] = rs[i][rg];
  }
  __syncthreads();
  if (t < 128) lpart[(size_t)nb * CH + by * 128 + t] = ps[t] + ps[128 + t];
}

// ---------------- k_pv: Op[z] = E @ embT^T (uneven K-split) --------------
__global__ __launch_bounds__(256, 2) void k_pv(const f16* __restrict__ A,
                                               const f16* __restrict__ Bt,
                                               float* __restrict__ Op,
                                               int CH) {
  __shared__ f16 sm[2][12288];
  const int t = threadIdx.x;
  const int w = t >> 6, l = t & 63;
  const int lr = l & 15, lg = l >> 4;
  const int wr = w >> 1, wc = w & 1;
  const int mB = CH >> 7;
  const int nwg = 2 * mB * KS;
  const int o = blockIdx.x + blockIdx.y * 2 + blockIdx.z * 2 * mB;
  const int v = (o & 7) * (nwg >> 3) + (o >> 3);
  const int m = v % mB;
  const int rest = v / mB;
  const int n = rest & 1, z = rest >> 1;
  const int n0 = n * 256;
  const int m0 = m * 128;
  const int g0 = z * 96 + (z < 8 ? z : 8);
  const int ng = 96 + (z < 8 ? 1 : 0);
  const size_t kb = (size_t)g0 * 32;

  const int rA1 = t >> 2, qA1 = t & 3;
  const int rA2 = (t + 256) >> 2;
  const int qsA1 = qA1 ^ ((rA1 >> 1) & 3);
  const int qsA2 = qA1 ^ ((rA2 >> 1) & 3);
  const f16* gA1 = A + (size_t)(m0 + rA1) * NV + kb + qsA1 * 8;
  const f16* gA2 = A + (size_t)(m0 + rA2) * NV + kb + qsA2 * 8;
  const f16* gB[4];
#pragma unroll
  for (int s = 0; s < 4; ++s) {
    int c = t + 256 * s;
    int r = c >> 2, q = c & 3;
    int qs = q ^ ((r >> 1) & 3);
    gB[s] = Bt + (size_t)(n0 + r) * NV + kb + qs * 8;
  }
  auto STAGE = [&](int buf, int k0) {
    gload16(gA1 + k0, (void*)&sm[buf][(size_t)t * 8]);
    gload16(gA2 + k0, (void*)&sm[buf][(size_t)(t + 256) * 8]);
    gload16(gB[0] + k0, (void*)&sm[buf][4096 + (size_t)t * 8]);
    gload16(gB[1] + k0, (void*)&sm[buf][4096 + (size_t)(t + 256) * 8]);
    gload16(gB[2] + k0, (void*)&sm[buf][4096 + (size_t)(t + 512) * 8]);
    gload16(gB[3] + k0, (void*)&sm[buf][4096 + (size_t)(t + 768) * 8]);
  };
  const int gsw = lg ^ ((lr >> 1) & 3);

  f32x4 acc[4][8];
#pragma unroll
  for (int i = 0; i < 4; ++i)
#pragma unroll
    for (int j = 0; j < 8; ++j) acc[i][j] = (f32x4){0.f, 0.f, 0.f, 0.f};

  STAGE(0, 0);
  STAGE(1, 32);
  asm volatile("s_waitcnt vmcnt(6)" ::: "memory"); SCHED0();
  SBAR(); SCHED0();
  int cur = 0;
  for (int it = 0; it < ng; ++it) {
    const f16* bufA = sm[cur];
    const f16* bufB = sm[cur] + 4096;
    f16x8 af[4], bf[8];
#pragma unroll
    for (int i = 0; i < 4; ++i)
      af[i] = *(const f16x8*)&bufA[(wr * 64 + i * 16 + lr) * 32 + gsw * 8];
#pragma unroll
    for (int j = 0; j < 8; ++j)
      bf[j] = *(const f16x8*)&bufB[(wc * 128 + j * 16 + lr) * 32 + gsw * 8];
#pragma unroll
    for (int i = 0; i < 4; ++i)
#pragma unroll
      for (int j = 0; j < 8; ++j)
        acc[i][j] = __builtin_amdgcn_mfma_f32_16x16x32_f16(af[i], bf[j], acc[i][j], 0, 0, 0);
    asm volatile("s_waitcnt lgkmcnt(0)" ::: "memory"); SCHED0();
    SBAR(); SCHED0();
    if (it + 2 < ng) {
      STAGE(cur, (it + 2) * 32);
      asm volatile("s_waitcnt vmcnt(6)" ::: "memory");
    } else {
      asm volatile("s_waitcnt vmcnt(0)" ::: "memory");
    }
    SCHED0();
    SBAR(); SCHED0();
    cur ^= 1;
  }

#pragma unroll
  for (int i = 0; i < 4; ++i)
#pragma unroll
    for (int j = 0; j < 8; ++j)
#pragma unroll
      for (int rg = 0; rg < 4; ++rg) {
        int row = m0 + wr * 64 + i * 16 + lg * 4 + rg;
        int col = n0 + wc * 128 + j * 16 + lr;
        Op[((size_t)z * CH + row) * DT + col] = acc[i][j][rg];
      }
}

// ---------------- l[r] = sum over vocab of E -----------------------------
__global__ __launch_bounds__(256) void k_lred(const float* __restrict__ lp,
                                              float* __restrict__ lv, int CH) {
  int rb = blockIdx.x * 256 + threadIdx.x;
  float s = 0.f;
  for (int nb = 0; nb < NB_N; ++nb) s += lp[(size_t)nb * CH + rb];
  lv[rb] = s;
}

// ---------------- combine split-K + divide by l --------------------------
__global__ __launch_bounds__(256) void k_out(const float* __restrict__ Op,
                                             const float* __restrict__ lv,
                                             float* __restrict__ out,
                                             int row0, int CH) {
  int idx = blockIdx.x * 256 + threadIdx.x;
  int rb = idx >> 9, c = idx & 511;
  float s = 0.f;
#pragma unroll
  for (int z = 0; z < KS; ++z) s += Op[((size_t)z * CH + rb) * DT + c];
  out[(size_t)(row0 + rb) * DT + c] = s / lv[rb];
}

extern "C" void kernel_launch(void* const* d_in, const int* in_sizes, int n_in,
                              void* d_out, int out_size, void* d_ws, size_t ws_size,
                              hipStream_t stream) {
  const float* audio = (const float*)d_in[0];
  const float* W     = (const float*)d_in[1];
  const float* bias  = (const float*)d_in[2];
  const float* gamma = (const float*)d_in[3];
  const float* beta  = (const float*)d_in[4];
  const float* emb   = (const float*)d_in[5];
  float* out = (float*)d_out;

  char* ws = (char*)d_ws;
  size_t off = 0;
  auto alloc = [&](size_t bytes) {
    char* p = ws + off;
    off += (bytes + 255) & ~(size_t)255;
    return p;
  };
  float* proj  = (float*)alloc((size_t)MTOT * DT * 4);
  float* pstat = (float*)alloc((size_t)64 * 1024 * 4);
  float* stats = (float*)alloc((size_t)2 * DT * 4);
  u16*   bnnH  = (u16*)alloc((size_t)MTOT * DT * 2);
  u16*   embH  = (u16*)alloc((size_t)NV * DT * 2);
  u16*   embT  = (u16*)alloc((size_t)DT * NV * 2);
  float* invn  = (float*)alloc((size_t)NV * 4);
  size_t fixed_off = off;

  int CH = 2048;
  while (CH > 256) {
    size_t need = fixed_off;
    need += (((size_t)CH * NV * 2) + 255) & ~(size_t)255;          // E
    need += (((size_t)NB_N * CH * 4) + 255) & ~(size_t)255;        // lpart
    need += (((size_t)CH * 4) + 255) & ~(size_t)255;               // lvec
    need += (((size_t)KS * CH * DT * 4) + 255) & ~(size_t)255;     // Op
    if (need <= ws_size) break;
    CH >>= 1;
  }
  u16*   E     = (u16*)alloc((size_t)CH * NV * 2);
  float* lpart = (float*)alloc((size_t)NB_N * CH * 4);
  float* lvec  = (float*)alloc((size_t)CH * 4);
  float* Op    = (float*)alloc((size_t)KS * CH * DT * 4);
  if (ws_size < off) return;

  k_proj<<<dim3(32, 8), dim3(256), 0, stream>>>(audio, W, bias, proj);
  k_stats<<<dim3(64), dim3(256), 0, stream>>>(proj, pstat);
  k_stats2<<<dim3(4), dim3(256), 0, stream>>>(pstat, stats);
  k_bnnorm<<<dim3(MTOT), dim3(64), 0, stream>>>(proj, stats, gamma, beta, bnnH);
  k_embprep<<<dim3(NV / 4), dim3(256), 0, stream>>>(emb, embH, invn);
  k_embT<<<dim3(NV / 64, DT / 64), dim3(256), 0, stream>>>(emb, embT);

  for (int row0 = 0; row0 < MTOT; row0 += CH) {
    k_score<<<dim3(NB_N, CH / 128), dim3(256), 0, stream>>>(
        (const f16*)bnnH, (const f16*)embH, invn, E, lpart, row0, CH);
    k_lred<<<dim3(CH / 256), dim3(256), 0, stream>>>(lpart, lvec, CH);
    k_pv<<<dim3(2, CH / 128, KS), dim3(256), 0, stream>>>(
        (const f16*)E, (const f16*)embT, Op, CH);
    k_out<<<dim3(CH * 2), dim3(256), 0, stream>>>(Op, lvec, out, row0, CH);
  }
}

// Round 5
// 435.313 us; speedup vs baseline: 1.5090x; 1.0167x over previous
//
#include <hip/hip_runtime.h>
#include <stdint.h>

typedef unsigned short u16;
typedef _Float16 f16;
typedef __attribute__((ext_vector_type(8))) _Float16 f16x8;
typedef __attribute__((ext_vector_type(4))) float f32x4;

#define DA 768
#define DT 512
#define NV 49408
#define MTOT 2048
#define NB2 193           // NV / 256  (n-tiles for k_score)
#define KS 16             // k_pv K-split (slices of 49/48 K64-tiles)

__device__ __forceinline__ u16 f2h(float f) {
  return __builtin_bit_cast(u16, (f16)f);
}

__device__ __forceinline__ void gload16(const void* g, void* l) {
  __builtin_amdgcn_global_load_lds((const __attribute__((address_space(1))) void*)g,
                                   (__attribute__((address_space(3))) void*)l,
                                   16, 0, 0);
}
#define SBAR()   __builtin_amdgcn_s_barrier()
#define SCHED0() __builtin_amdgcn_sched_barrier(0)

// ---------------- proj = audio @ W + b (fp32, 64x64 tile) ----------------
__global__ __launch_bounds__(256) void k_proj(const float* __restrict__ A,
                                              const float* __restrict__ W,
                                              const float* __restrict__ bias,
                                              float* __restrict__ P) {
  __shared__ float As[16][72];
  __shared__ float Bs[16][72];
  const int m0 = blockIdx.x * 64, n0 = blockIdx.y * 64;
  const int t = threadIdx.x;
  const int ty = t >> 4, tx = t & 15;
  const int ar = t >> 2, ak = (t & 3) * 4;
  const int bk = t >> 4, bn = (t & 15) * 4;
  float acc[4][4] = {};
  for (int k0 = 0; k0 < DA; k0 += 16) {
    float4 av = *(const float4*)&A[(size_t)(m0 + ar) * DA + k0 + ak];
    float4 bv = *(const float4*)&W[(size_t)(k0 + bk) * DT + n0 + bn];
    __syncthreads();
    As[ak + 0][ar] = av.x; As[ak + 1][ar] = av.y;
    As[ak + 2][ar] = av.z; As[ak + 3][ar] = av.w;
    *(float4*)&Bs[bk][bn] = bv;
    __syncthreads();
#pragma unroll
    for (int kk = 0; kk < 16; ++kk) {
      float4 a4 = *(const float4*)&As[kk][ty * 4];
      float4 b4 = *(const float4*)&Bs[kk][tx * 4];
      float ae[4] = {a4.x, a4.y, a4.z, a4.w};
      float be[4] = {b4.x, b4.y, b4.z, b4.w};
#pragma unroll
      for (int i = 0; i < 4; ++i)
#pragma unroll
        for (int j = 0; j < 4; ++j) acc[i][j] = fmaf(ae[i], be[j], acc[i][j]);
    }
  }
#pragma unroll
  for (int i = 0; i < 4; ++i) {
    int row = m0 + ty * 4 + i;
    float4 o;
    o.x = acc[i][0] + bias[n0 + tx * 4 + 0];
    o.y = acc[i][1] + bias[n0 + tx * 4 + 1];
    o.z = acc[i][2] + bias[n0 + tx * 4 + 2];
    o.w = acc[i][3] + bias[n0 + tx * 4 + 3];
    *(float4*)&P[(size_t)row * DT + n0 + tx * 4] = o;
  }
}

// ---------------- BN stats ----------------------------------------------
__global__ __launch_bounds__(256) void k_stats(const float* __restrict__ P,
                                               float* __restrict__ pstat) {
  const int t = threadIdx.x;
  const int r0 = blockIdx.x * 32;
  float s0 = 0, q0 = 0, s1 = 0, q1 = 0;
  for (int r = r0; r < r0 + 32; ++r) {
    float x0 = P[(size_t)r * DT + t];
    float x1 = P[(size_t)r * DT + t + 256];
    s0 += x0; q0 += x0 * x0; s1 += x1; q1 += x1 * x1;
  }
  float* d = pstat + (size_t)blockIdx.x * 1024;
  d[t] = s0; d[t + 256] = s1; d[512 + t] = q0; d[768 + t] = q1;
}

__global__ __launch_bounds__(256) void k_stats2(const float* __restrict__ pstat,
                                                float* __restrict__ stats) {
  int c = blockIdx.x * 256 + threadIdx.x;
  float s = 0.f;
  for (int b = 0; b < 64; ++b) s += pstat[(size_t)b * 1024 + c];
  stats[c] = s;
}

// ---------------- BN apply + row L2 normalize -> f16 ---------------------
__global__ __launch_bounds__(64) void k_bnnorm(const float* __restrict__ P,
                                               const float* __restrict__ stats,
                                               const float* __restrict__ gamma,
                                               const float* __restrict__ beta,
                                               u16* __restrict__ bnn) {
  const int r = blockIdx.x, l = threadIdx.x;
  float v[8];
  float ss = 0.f;
#pragma unroll
  for (int i = 0; i < 8; ++i) {
    int c = l * 8 + i;
    float mean = stats[c] * (1.f / MTOT);
    float var = stats[DT + c] * (1.f / MTOT) - mean * mean;
    float is = rsqrtf(var + 1e-5f);
    float x = (P[(size_t)r * DT + c] - mean) * is * gamma[c] + beta[c];
    v[i] = x; ss += x * x;
  }
#pragma unroll
  for (int off = 32; off > 0; off >>= 1) ss += __shfl_xor(ss, off);
  float rn = rsqrtf(ss);
  union { u16 u[8]; int4 q; } pk;
#pragma unroll
  for (int i = 0; i < 8; ++i) pk.u[i] = f2h(v[i] * rn);
  *(int4*)&bnn[(size_t)r * DT + l * 8] = pk.q;
}

// ---------------- emb -> f16 rows + 10/||emb|| ---------------------------
__global__ __launch_bounds__(256) void k_embprep(const float* __restrict__ emb,
                                                 u16* __restrict__ embH,
                                                 float* __restrict__ invn) {
  const int w = threadIdx.x >> 6, l = threadIdx.x & 63;
  const int vrow = blockIdx.x * 4 + w;
  const float* src = emb + (size_t)vrow * DT + l * 8;
  float4 a = *(const float4*)src;
  float4 b = *(const float4*)(src + 4);
  float x[8] = {a.x, a.y, a.z, a.w, b.x, b.y, b.z, b.w};
  float ss = 0.f;
#pragma unroll
  for (int i = 0; i < 8; ++i) ss += x[i] * x[i];
#pragma unroll
  for (int off = 32; off > 0; off >>= 1) ss += __shfl_xor(ss, off);
  if (l == 0) invn[vrow] = rsqrtf(ss) * 10.0f;
  union { u16 u[8]; int4 q; } pk;
#pragma unroll
  for (int i = 0; i < 8; ++i) pk.u[i] = f2h(x[i]);
  *(int4*)&embH[(size_t)vrow * DT + l * 8] = pk.q;
}

// ---------------- embT[d][v] = f16(emb[v][d]) ----------------------------
__global__ __launch_bounds__(256) void k_embT(const float* __restrict__ emb,
                                              u16* __restrict__ embT) {
  __shared__ float tile[64][65];
  const int v0 = blockIdx.x * 64, d0 = blockIdx.y * 64;
  const int t = threadIdx.x;
  {
    const int r = t >> 4, c = (t & 15) * 4;
#pragma unroll
    for (int i = 0; i < 4; ++i) {
      float4 x = *(const float4*)&emb[(size_t)(v0 + r + i * 16) * DT + d0 + c];
      tile[r + i * 16][c + 0] = x.x; tile[r + i * 16][c + 1] = x.y;
      tile[r + i * 16][c + 2] = x.z; tile[r + i * 16][c + 3] = x.w;
    }
  }
  __syncthreads();
  {
    const int d = t >> 2;
    const int vc = (t & 3) * 16;
    union { u16 u[8]; int4 q; } p0, p1;
#pragma unroll
    for (int i = 0; i < 8; ++i) p0.u[i] = f2h(tile[vc + i][d]);
#pragma unroll
    for (int i = 0; i < 8; ++i) p1.u[i] = f2h(tile[vc + 8 + i][d]);
    u16* dst = embT + (size_t)(d0 + d) * NV + v0 + vc;
    *(int4*)dst = p0.q;
    *(int4*)(dst + 8) = p1.q;
  }
}

// ============ 256x256 8-phase-style pipelined K-loop (shared) ============
// 512 thr, 8 waves (2M x 4N), wave-tile 128x64, BK=64, LDS 128 KiB dbuf.
// Phase walk (af,bf) = (R0,C0)->(R0,C1)->(R1,C1)->(R1,C0); acc quadrant
// MATCHES fragment contents (round-4 bug: it didn't).
// Stage rotation: p0:B0(t+1)  p1:B1(t+1)  p2:A(t+2)q0q2  p3:A(t+2)q1q3.
// Single counted vmcnt(4) per K-tile at p3 (FIFO-verified).

#define MFMA_BLK(IH, JH)                                                     \
  _Pragma("unroll")                                                          \
  for (int ii = 0; ii < 4; ++ii) {                                           \
    _Pragma("unroll")                                                        \
    for (int jj = 0; jj < 2; ++jj) {                                         \
      acc[(IH)*4+ii][(JH)*2+jj] = __builtin_amdgcn_mfma_f32_16x16x32_f16(    \
          af[ii][0], bf[jj][0], acc[(IH)*4+ii][(JH)*2+jj], 0, 0, 0);         \
      acc[(IH)*4+ii][(JH)*2+jj] = __builtin_amdgcn_mfma_f32_16x16x32_f16(    \
          af[ii][1], bf[jj][1], acc[(IH)*4+ii][(JH)*2+jj], 0, 0, 0);         \
    }                                                                        \
  }

__device__ __forceinline__ void gemm_kloop(const f16* __restrict__ A,
                                           const f16* __restrict__ B,
                                           int lda, int ldb, size_t kb,
                                           int NT, int m0, int n0,
                                           char* lds, int tid,
                                           f32x4 (&acc)[8][4]) {
  const int l = tid & 63, lr = l & 15, lg = l >> 4;
  const int w = tid >> 6, wm = w >> 2, wn = w & 3;
  const int r8 = tid >> 3;
  const int gs = (tid & 7) ^ (r8 & 7);          // pre-swizzled source granule
  const f16* aRow = A + (size_t)(m0 + r8) * lda + kb + gs * 8;
  const f16* bRow = B + (size_t)(n0 + r8) * ldb + kb + gs * 8;
  char* ldsA = lds;
  char* ldsB = lds + 65536;
  char* dstA = ldsA + tid * 16;
  char* dstB = ldsB + tid * 16;
  const int gx0 = ((lg ^ (lr & 7)) << 4);       // read-side granule swizzle
  const int gx1 = (((4 + lg) ^ (lr & 7)) << 4);
  const int aoff = (wm * 128 + lr) * 128;
  const int boff = (wn * 64 + lr) * 128;

#define STA(sl, q, kt) gload16(aRow + (size_t)(q) * 64 * lda + (size_t)(kt) * 64, \
                               dstA + (sl) * 32768 + (q) * 8192)
#define STB(sl, h, ql, kt) gload16(bRow + (size_t)((h) * 128 + (ql) * 64) * ldb + (size_t)(kt) * 64, \
                                   dstB + (sl) * 32768 + (h) * 16384 + (ql) * 8192)
#define RDA(IH)                                                              \
  _Pragma("unroll")                                                          \
  for (int ii = 0; ii < 4; ++ii) {                                           \
    af[ii][0] = *(const f16x8*)(As + ((IH)*4+ii) * 2048 + aoff + gx0);       \
    af[ii][1] = *(const f16x8*)(As + ((IH)*4+ii) * 2048 + aoff + gx1);       \
  }
#define RDB(JH)                                                              \
  _Pragma("unroll")                                                          \
  for (int jj = 0; jj < 2; ++jj) {                                           \
    bf[jj][0] = *(const f16x8*)(Bs + ((JH)*2+jj) * 2048 + boff + gx0);       \
    bf[jj][1] = *(const f16x8*)(Bs + ((JH)*2+jj) * 2048 + boff + gx1);       \
  }

  // prologue: tile0 full + A(1) quarters; wait so only A(1) stays in flight
  STA(0, 0, 0); STA(0, 1, 0); STA(0, 2, 0); STA(0, 3, 0);
  STB(0, 0, 0, 0); STB(0, 0, 1, 0); STB(0, 1, 0, 0); STB(0, 1, 1, 0);
  if (NT > 1) {
    STA(1, 0, 1); STA(1, 2, 1); STA(1, 1, 1); STA(1, 3, 1);
    asm volatile("s_waitcnt vmcnt(4)" ::: "memory");
  } else {
    asm volatile("s_waitcnt vmcnt(0)" ::: "memory");
  }
  SCHED0();
  SBAR(); SCHED0();

  f16x8 af[4][2], bf[2][2];
  for (int t = 0; t < NT; ++t) {
    const int sl = t & 1, ns = sl ^ 1;
    char* As = ldsA + sl * 32768;
    char* Bs = ldsB + sl * 32768;
    const bool s1 = (t + 1 < NT), s2 = (t + 2 < NT);
    // ---- phase 0: af=R0, bf=C0; stage B0(t+1); mfma acc[R0][C0]
    RDA(0); RDB(0);
    if (s1) { STB(ns, 0, 0, t + 1); STB(ns, 0, 1, t + 1); }
    SBAR();
    asm volatile("s_waitcnt lgkmcnt(0)" ::: "memory"); SCHED0();
    __builtin_amdgcn_s_setprio(1);
    MFMA_BLK(0, 0);
    __builtin_amdgcn_s_setprio(0);
    SBAR(); SCHED0();
    // ---- phase 1: bf=C1; stage B1(t+1); mfma acc[R0][C1]
    RDB(1);
    if (s1) { STB(ns, 1, 0, t + 1); STB(ns, 1, 1, t + 1); }
    SBAR();
    asm volatile("s_waitcnt lgkmcnt(0)" ::: "memory"); SCHED0();
    __builtin_amdgcn_s_setprio(1);
    MFMA_BLK(0, 1);
    __builtin_amdgcn_s_setprio(0);
    SBAR(); SCHED0();
    // ---- phase 2: af=R1; stage A(t+2) q0,q2; mfma acc[R1][C1]
    RDA(1);
    if (s2) { STA(sl, 0, t + 2); STA(sl, 2, t + 2); }
    SBAR();
    asm volatile("s_waitcnt lgkmcnt(0)" ::: "memory"); SCHED0();
    __builtin_amdgcn_s_setprio(1);
    MFMA_BLK(1, 1);
    __builtin_amdgcn_s_setprio(0);
    SBAR(); SCHED0();
    // ---- phase 3: bf=C0 re-read; stage A(t+2) q1,q3; vmcnt; mfma acc[R1][C0]
    RDB(0);
    if (s2) { STA(sl, 1, t + 2); STA(sl, 3, t + 2); }
    SBAR();
    asm volatile("s_waitcnt lgkmcnt(0)" ::: "memory"); SCHED0();
    __builtin_amdgcn_s_setprio(1);
    MFMA_BLK(1, 0);
    __builtin_amdgcn_s_setprio(0);
    if (s2) asm volatile("s_waitcnt vmcnt(4)" ::: "memory");
    else    asm volatile("s_waitcnt vmcnt(0)" ::: "memory");
    SCHED0();
    SBAR(); SCHED0();
  }
#undef STA
#undef STB
#undef RDA
#undef RDB
}

// ---------------- k_score: E = exp(invn * (bnnH @ embH^T)) ---------------
__global__ __launch_bounds__(512, 2) void k_score(const f16* __restrict__ A,
                                                  const f16* __restrict__ Bt,
                                                  const float* __restrict__ invn,
                                                  u16* __restrict__ E,
                                                  float* __restrict__ lpart,
                                                  int row0, int CH) {
  extern __shared__ char lds[];
  const int t = threadIdx.x;
  const int l = t & 63, lr = l & 15, lg = l >> 4;
  const int w = t >> 6, wm = w >> 2, wn = w & 3;
  const int mB = CH >> 8;
  const int nwg = NB2 * mB;
  const int o = blockIdx.x + blockIdx.y * gridDim.x;
  const int qd = nwg >> 3, r = nwg & 7;
  const int xcd = o & 7, idx = o >> 3;
  const int v = (xcd < r ? xcd * (qd + 1) : r * (qd + 1) + (xcd - r) * qd) + idx;
  const int nb = v % NB2, by = v / NB2;
  const int n0 = nb * 256;
  const int mloc = by * 256;

  f32x4 acc[8][4];
#pragma unroll
  for (int i = 0; i < 8; ++i)
#pragma unroll
    for (int j = 0; j < 4; ++j) acc[i][j] = (f32x4){0.f, 0.f, 0.f, 0.f};

  gemm_kloop(A, Bt, DT, DT, 0, DT / 64, row0 + mloc, n0, lds, t, acc);

  // ---- epilogue: exp, bounce to LDS (reused), coalesced E store, row sums
  float* psum = (float*)(lds + 131072);
  float inv_j[4];
#pragma unroll
  for (int j = 0; j < 4; ++j) inv_j[j] = invn[n0 + wn * 64 + j * 16 + lr];
#pragma unroll
  for (int i = 0; i < 8; ++i) {
#pragma unroll
    for (int rg = 0; rg < 4; ++rg) {
      int row = wm * 128 + i * 16 + lg * 4 + rg;
      float rs = 0.f;
#pragma unroll
      for (int j = 0; j < 4; ++j) {
        float e = __expf(acc[i][j][rg] * inv_j[j]);
        rs += e;
        int col = wn * 64 + j * 16 + lr;
        int g4 = col >> 3;
        *(u16*)(lds + row * 512 + ((g4 ^ lg) << 4) + (col & 7) * 2) = f2h(e);
      }
#pragma unroll
      for (int m = 1; m <= 8; m <<= 1) rs += __shfl_xor(rs, m);
      if (lr == 0) psum[w * 128 + i * 16 + lg * 4 + rg] = rs;
    }
  }
  __syncthreads();
#pragma unroll
  for (int cc = 0; cc < 16; ++cc) {
    int lin = cc * 512 + t;
    int row = lin >> 5, g4 = lin & 31;
    int4 vv = *(const int4*)(lds + row * 512 + ((g4 ^ ((row >> 2) & 3)) << 4));
    *(int4*)&E[(size_t)(mloc + row) * NV + n0 + g4 * 8] = vv;
  }
  if (t < 256) {
    int wmx = t >> 7, rl = t & 127;
    float s = psum[(wmx * 4 + 0) * 128 + rl] + psum[(wmx * 4 + 1) * 128 + rl] +
              psum[(wmx * 4 + 2) * 128 + rl] + psum[(wmx * 4 + 3) * 128 + rl];
    lpart[(size_t)nb * CH + mloc + t] = s;
  }
}

// ---------------- k_pv: Op[z] = E @ embT^T (uneven K-split) --------------
__global__ __launch_bounds__(512, 2) void k_pv(const f16* __restrict__ A,
                                               const f16* __restrict__ Bt,
                                               float* __restrict__ Op,
                                               int CH) {
  extern __shared__ char lds[];
  const int t = threadIdx.x;
  const int l = t & 63, lr = l & 15, lg = l >> 4;
  const int w = t >> 6, wm = w >> 2, wn = w & 3;
  const int n0 = blockIdx.x * 256;
  const int mloc = blockIdx.y * 256;
  const int z = blockIdx.z;
  const int g0 = z * 48 + (z < 4 ? z : 4);
  const int NT = 48 + (z < 4 ? 1 : 0);
  const size_t kb = (size_t)g0 * 64;

  f32x4 acc[8][4];
#pragma unroll
  for (int i = 0; i < 8; ++i)
#pragma unroll
    for (int j = 0; j < 4; ++j) acc[i][j] = (f32x4){0.f, 0.f, 0.f, 0.f};

  gemm_kloop(A, Bt, NV, NV, kb, NT, mloc, n0, lds, t, acc);

#pragma unroll
  for (int i = 0; i < 8; ++i)
#pragma unroll
    for (int j = 0; j < 4; ++j)
#pragma unroll
      for (int rg = 0; rg < 4; ++rg) {
        int row = mloc + wm * 128 + i * 16 + lg * 4 + rg;
        int col = n0 + wn * 64 + j * 16 + lr;
        Op[((size_t)z * CH + row) * DT + col] = acc[i][j][rg];
      }
}

// ---------------- l[r] = sum over vocab of E -----------------------------
__global__ __launch_bounds__(256) void k_lred(const float* __restrict__ lp,
                                              float* __restrict__ lv, int CH) {
  int rb = blockIdx.x * 256 + threadIdx.x;
  float s = 0.f;
  for (int nb = 0; nb < NB2; ++nb) s += lp[(size_t)nb * CH + rb];
  lv[rb] = s;
}

// ---------------- combine split-K + divide by l --------------------------
__global__ __launch_bounds__(256) void k_out(const float* __restrict__ Op,
                                             const float* __restrict__ lv,
                                             float* __restrict__ out,
                                             int row0, int CH) {
  int idx = blockIdx.x * 256 + threadIdx.x;
  int rb = idx >> 9, c = idx & 511;
  float s = 0.f;
#pragma unroll
  for (int zz = 0; zz < KS; ++zz) s += Op[((size_t)zz * CH + rb) * DT + c];
  out[(size_t)(row0 + rb) * DT + c] = s / lv[rb];
}

extern "C" void kernel_launch(void* const* d_in, const int* in_sizes, int n_in,
                              void* d_out, int out_size, void* d_ws, size_t ws_size,
                              hipStream_t stream) {
  const float* audio = (const float*)d_in[0];
  const float* W     = (const float*)d_in[1];
  const float* bias  = (const float*)d_in[2];
  const float* gamma = (const float*)d_in[3];
  const float* beta  = (const float*)d_in[4];
  const float* emb   = (const float*)d_in[5];
  float* out = (float*)d_out;

  char* ws = (char*)d_ws;
  size_t off = 0;
  auto alloc = [&](size_t bytes) {
    char* p = ws + off;
    off += (bytes + 255) & ~(size_t)255;
    return p;
  };
  float* proj  = (float*)alloc((size_t)MTOT * DT * 4);
  float* pstat = (float*)alloc((size_t)64 * 1024 * 4);
  float* stats = (float*)alloc((size_t)2 * DT * 4);
  u16*   bnnH  = (u16*)alloc((size_t)MTOT * DT * 2);
  u16*   embH  = (u16*)alloc((size_t)NV * DT * 2);
  u16*   embT  = (u16*)alloc((size_t)DT * NV * 2);
  float* invn  = (float*)alloc((size_t)NV * 4);
  size_t fixed_off = off;

  int CH = 2048;
  while (CH > 256) {
    size_t need = fixed_off;
    need += (((size_t)CH * NV * 2) + 255) & ~(size_t)255;          // E
    need += (((size_t)NB2 * CH * 4) + 255) & ~(size_t)255;         // lpart
    need += (((size_t)CH * 4) + 255) & ~(size_t)255;               // lvec
    need += (((size_t)KS * CH * DT * 4) + 255) & ~(size_t)255;     // Op
    if (need <= ws_size) break;
    CH >>= 1;
  }
  u16*   E     = (u16*)alloc((size_t)CH * NV * 2);
  float* lpart = (float*)alloc((size_t)NB2 * CH * 4);
  float* lvec  = (float*)alloc((size_t)CH * 4);
  float* Op    = (float*)alloc((size_t)KS * CH * DT * 4);
  if (ws_size < off) return;

  hipFuncSetAttribute((const void*)k_score,
                      hipFuncAttributeMaxDynamicSharedMemorySize, 135168);
  hipFuncSetAttribute((const void*)k_pv,
                      hipFuncAttributeMaxDynamicSharedMemorySize, 131072);

  k_proj<<<dim3(32, 8), dim3(256), 0, stream>>>(audio, W, bias, proj);
  k_stats<<<dim3(64), dim3(256), 0, stream>>>(proj, pstat);
  k_stats2<<<dim3(4), dim3(256), 0, stream>>>(pstat, stats);
  k_bnnorm<<<dim3(MTOT), dim3(64), 0, stream>>>(proj, stats, gamma, beta, bnnH);
  k_embprep<<<dim3(NV / 4), dim3(256), 0, stream>>>(emb, embH, invn);
  k_embT<<<dim3(NV / 64, DT / 64), dim3(256), 0, stream>>>(emb, embT);

  for (int row0 = 0; row0 < MTOT; row0 += CH) {
    k_score<<<dim3(NB2, CH / 256), dim3(512), 135168, stream>>>(
        (const f16*)bnnH, (const f16*)embH, invn, E, lpart, row0, CH);
    k_lred<<<dim3(CH / 256), dim3(256), 0, stream>>>(lpart, lvec, CH);
    k_pv<<<dim3(2, CH / 256, KS), dim3(512), 131072, stream>>>(
        (const f16*)E, (const f16*)embT, Op, CH);
    k_out<<<dim3(CH * 2), dim3(256), 0, stream>>>(Op, lvec, out, row0, CH);
  }
}

// Round 6
// 435.029 us; speedup vs baseline: 1.5100x; 1.0007x over previous
//
#include <hip/hip_runtime.h>
#include <stdint.h>

typedef unsigned short u16;
typedef _Float16 f16;
typedef __attribute__((ext_vector_type(8))) _Float16 f16x8;
typedef __attribute__((ext_vector_type(4))) float f32x4;

#define DA 768
#define DT 512
#define NV 49408
#define MTOT 2048
#define NB2 193           // NV / 256  (n-tiles for k_score)
#define KS 16             // k_pv K-split (slices of 49/48 K64-tiles)

__device__ __forceinline__ u16 f2h(float f) {
  return __builtin_bit_cast(u16, (f16)f);
}

__device__ __forceinline__ void gload16(const void* g, void* l) {
  __builtin_amdgcn_global_load_lds((const __attribute__((address_space(1))) void*)g,
                                   (__attribute__((address_space(3))) void*)l,
                                   16, 0, 0);
}
#define SBAR()   __builtin_amdgcn_s_barrier()
#define SCHED0() __builtin_amdgcn_sched_barrier(0)
#define MFMA16(a, b, c) __builtin_amdgcn_mfma_f32_16x16x32_f16((a), (b), (c), 0, 0, 0)

// ---------------- proj = audio @ W + b (fp32, 64x64 tile) ----------------
__global__ __launch_bounds__(256) void k_proj(const float* __restrict__ A,
                                              const float* __restrict__ W,
                                              const float* __restrict__ bias,
                                              float* __restrict__ P) {
  __shared__ float As[16][72];
  __shared__ float Bs[16][72];
  const int m0 = blockIdx.x * 64, n0 = blockIdx.y * 64;
  const int t = threadIdx.x;
  const int ty = t >> 4, tx = t & 15;
  const int ar = t >> 2, ak = (t & 3) * 4;
  const int bk = t >> 4, bn = (t & 15) * 4;
  float acc[4][4] = {};
  for (int k0 = 0; k0 < DA; k0 += 16) {
    float4 av = *(const float4*)&A[(size_t)(m0 + ar) * DA + k0 + ak];
    float4 bv = *(const float4*)&W[(size_t)(k0 + bk) * DT + n0 + bn];
    __syncthreads();
    As[ak + 0][ar] = av.x; As[ak + 1][ar] = av.y;
    As[ak + 2][ar] = av.z; As[ak + 3][ar] = av.w;
    *(float4*)&Bs[bk][bn] = bv;
    __syncthreads();
#pragma unroll
    for (int kk = 0; kk < 16; ++kk) {
      float4 a4 = *(const float4*)&As[kk][ty * 4];
      float4 b4 = *(const float4*)&Bs[kk][tx * 4];
      float ae[4] = {a4.x, a4.y, a4.z, a4.w};
      float be[4] = {b4.x, b4.y, b4.z, b4.w};
#pragma unroll
      for (int i = 0; i < 4; ++i)
#pragma unroll
        for (int j = 0; j < 4; ++j) acc[i][j] = fmaf(ae[i], be[j], acc[i][j]);
    }
  }
#pragma unroll
  for (int i = 0; i < 4; ++i) {
    int row = m0 + ty * 4 + i;
    float4 o;
    o.x = acc[i][0] + bias[n0 + tx * 4 + 0];
    o.y = acc[i][1] + bias[n0 + tx * 4 + 1];
    o.z = acc[i][2] + bias[n0 + tx * 4 + 2];
    o.w = acc[i][3] + bias[n0 + tx * 4 + 3];
    *(float4*)&P[(size_t)row * DT + n0 + tx * 4] = o;
  }
}

// ---------------- BN stats ----------------------------------------------
__global__ __launch_bounds__(256) void k_stats(const float* __restrict__ P,
                                               float* __restrict__ pstat) {
  const int t = threadIdx.x;
  const int r0 = blockIdx.x * 32;
  float s0 = 0, q0 = 0, s1 = 0, q1 = 0;
  for (int r = r0; r < r0 + 32; ++r) {
    float x0 = P[(size_t)r * DT + t];
    float x1 = P[(size_t)r * DT + t + 256];
    s0 += x0; q0 += x0 * x0; s1 += x1; q1 += x1 * x1;
  }
  float* d = pstat + (size_t)blockIdx.x * 1024;
  d[t] = s0; d[t + 256] = s1; d[512 + t] = q0; d[768 + t] = q1;
}

__global__ __launch_bounds__(256) void k_stats2(const float* __restrict__ pstat,
                                                float* __restrict__ stats) {
  int c = blockIdx.x * 256 + threadIdx.x;
  float s = 0.f;
  for (int b = 0; b < 64; ++b) s += pstat[(size_t)b * 1024 + c];
  stats[c] = s;
}

// ---------------- BN apply + row L2 normalize -> f16 ---------------------
__global__ __launch_bounds__(64) void k_bnnorm(const float* __restrict__ P,
                                               const float* __restrict__ stats,
                                               const float* __restrict__ gamma,
                                               const float* __restrict__ beta,
                                               u16* __restrict__ bnn) {
  const int r = blockIdx.x, l = threadIdx.x;
  float v[8];
  float ss = 0.f;
#pragma unroll
  for (int i = 0; i < 8; ++i) {
    int c = l * 8 + i;
    float mean = stats[c] * (1.f / MTOT);
    float var = stats[DT + c] * (1.f / MTOT) - mean * mean;
    float is = rsqrtf(var + 1e-5f);
    float x = (P[(size_t)r * DT + c] - mean) * is * gamma[c] + beta[c];
    v[i] = x; ss += x * x;
  }
#pragma unroll
  for (int off = 32; off > 0; off >>= 1) ss += __shfl_xor(ss, off);
  float rn = rsqrtf(ss);
  union { u16 u[8]; int4 q; } pk;
#pragma unroll
  for (int i = 0; i < 8; ++i) pk.u[i] = f2h(v[i] * rn);
  *(int4*)&bnn[(size_t)r * DT + l * 8] = pk.q;
}

// ------- fused emb prep: one pass -> embH (f16), embT (f16), invn --------
__global__ __launch_bounds__(256) void k_embprep2(const float* __restrict__ emb,
                                                  u16* __restrict__ embH,
                                                  u16* __restrict__ embT,
                                                  float* __restrict__ invn) {
  __shared__ float tile[64][65];
  const int v0 = blockIdx.x * 64;
  const int t = threadIdx.x;
  const int r = t >> 4, c4 = (t & 15) * 4;   // cooperative load
  const int vr = t >> 2, hc = (t & 3) * 16;  // embH write: row vr, 16 cols
  const int dr = t >> 2, vc = (t & 3) * 16;  // embT write: d-row dr, 16 v-cols
  float ssq = 0.f;
  for (int d0 = 0; d0 < DT; d0 += 64) {
    __syncthreads();
#pragma unroll
    for (int i = 0; i < 4; ++i) {
      float4 x = *(const float4*)&emb[(size_t)(v0 + r + i * 16) * DT + d0 + c4];
      tile[r + i * 16][c4 + 0] = x.x; tile[r + i * 16][c4 + 1] = x.y;
      tile[r + i * 16][c4 + 2] = x.z; tile[r + i * 16][c4 + 3] = x.w;
    }
    __syncthreads();
    union { u16 u[8]; int4 q; } pa, pb;
#pragma unroll
    for (int i = 0; i < 8; ++i) { float f = tile[vr][hc + i];     pa.u[i] = f2h(f); ssq += f * f; }
#pragma unroll
    for (int i = 0; i < 8; ++i) { float f = tile[vr][hc + 8 + i]; pb.u[i] = f2h(f); ssq += f * f; }
    *(int4*)&embH[(size_t)(v0 + vr) * DT + d0 + hc] = pa.q;
    *(int4*)&embH[(size_t)(v0 + vr) * DT + d0 + hc + 8] = pb.q;
    union { u16 u[8]; int4 q; } p0, p1;
#pragma unroll
    for (int i = 0; i < 8; ++i) p0.u[i] = f2h(tile[vc + i][dr]);
#pragma unroll
    for (int i = 0; i < 8; ++i) p1.u[i] = f2h(tile[vc + 8 + i][dr]);
    u16* dst = embT + (size_t)(d0 + dr) * NV + v0 + vc;
    *(int4*)dst = p0.q;
    *(int4*)(dst + 8) = p1.q;
  }
  // 4 consecutive threads share row vr -> shuffle-reduce
  ssq += __shfl_xor(ssq, 1);
  ssq += __shfl_xor(ssq, 2);
  if ((t & 3) == 0) invn[v0 + vr] = rsqrtf(ssq) * 10.0f;
}

// ======== 256x256 BK=64 K-loop: 1 barrier/tile, compiler-pipelined =======
// 512 thr, 8 waves (2M x 4N), wave-tile 128x64. LDS 128 KiB (A,B dbuf).
// Per tile: stage next tile (8 gload_lds, other buffer) -> 4 read/MFMA
// groups (counted lgkm by compiler) -> vmcnt(0) [free: loads issued ~2100
// cyc earlier] -> s_barrier.  Hazards audited: stage targets' last readers
// drained before the previous tile's barrier.

__device__ __forceinline__ void gemm_kloop(const f16* __restrict__ A,
                                           const f16* __restrict__ B,
                                           int lda, int ldb, size_t kb,
                                           int NT, int m0, int n0,
                                           char* lds, int tid,
                                           f32x4 (&acc)[8][4]) {
  const int l = tid & 63, lr = l & 15, lg = l >> 4;
  const int w = tid >> 6, wm = w >> 2, wn = w & 3;
  const int r8 = tid >> 3;
  const int gs = (tid & 7) ^ (r8 & 7);          // pre-swizzled source granule
  const f16* aRow = A + (size_t)(m0 + r8) * lda + kb + gs * 8;
  const f16* bRow = B + (size_t)(n0 + r8) * ldb + kb + gs * 8;
  char* ldsA = lds;
  char* ldsB = lds + 65536;
  char* dstA = ldsA + tid * 16;
  char* dstB = ldsB + tid * 16;
  const int gx0 = ((lg ^ (lr & 7)) << 4);       // read-side granule swizzle
  const int gx1 = (((4 + lg) ^ (lr & 7)) << 4);
  const int aoff = (wm * 128 + lr) * 128;
  const int boff = (wn * 64 + lr) * 128;

#define STA(sl, q, kt) gload16(aRow + (size_t)(q) * 64 * lda + (size_t)(kt) * 64, \
                               dstA + (sl) * 32768 + (q) * 8192)
#define STB(sl, q, kt) gload16(bRow + (size_t)(q) * 64 * ldb + (size_t)(kt) * 64, \
                               dstB + (sl) * 32768 + (q) * 8192)

  // prologue: tile 0 only; full drain + barrier
  STA(0, 0, 0); STA(0, 1, 0); STA(0, 2, 0); STA(0, 3, 0);
  STB(0, 0, 0); STB(0, 1, 0); STB(0, 2, 0); STB(0, 3, 0);
  asm volatile("s_waitcnt vmcnt(0)" ::: "memory");
  SCHED0();
  SBAR(); SCHED0();

  for (int t = 0; t < NT; ++t) {
    const int sl = t & 1, ns = sl ^ 1;
    const char* As = ldsA + sl * 32768;
    const char* Bs = ldsB + sl * 32768;
    // stage tile t+1 into the other buffer (its last readers finished
    // before the barrier that ended tile t-1)
    if (t + 1 < NT) {
      STA(ns, 0, t + 1); STA(ns, 1, t + 1); STA(ns, 2, t + 1); STA(ns, 3, t + 1);
      STB(ns, 0, t + 1); STB(ns, 1, t + 1); STB(ns, 2, t + 1); STB(ns, 3, t + 1);
    }
    // group 1: A rows 0-63 + B cols 0-31 -> acc[0..3][0..1]
    f16x8 a0[4][2], b0[2][2];
#pragma unroll
    for (int ii = 0; ii < 4; ++ii) {
      a0[ii][0] = *(const f16x8*)(As + ii * 2048 + aoff + gx0);
      a0[ii][1] = *(const f16x8*)(As + ii * 2048 + aoff + gx1);
    }
#pragma unroll
    for (int jj = 0; jj < 2; ++jj) {
      b0[jj][0] = *(const f16x8*)(Bs + jj * 2048 + boff + gx0);
      b0[jj][1] = *(const f16x8*)(Bs + jj * 2048 + boff + gx1);
    }
#pragma unroll
    for (int ii = 0; ii < 4; ++ii)
#pragma unroll
      for (int jj = 0; jj < 2; ++jj) {
        acc[ii][jj] = MFMA16(a0[ii][0], b0[jj][0], acc[ii][jj]);
        acc[ii][jj] = MFMA16(a0[ii][1], b0[jj][1], acc[ii][jj]);
      }
    // group 2: B cols 32-63 -> acc[0..3][2..3]  (read latency hides under g1)
    f16x8 b1[2][2];
#pragma unroll
    for (int jj = 0; jj < 2; ++jj) {
      b1[jj][0] = *(const f16x8*)(Bs + (2 + jj) * 2048 + boff + gx0);
      b1[jj][1] = *(const f16x8*)(Bs + (2 + jj) * 2048 + boff + gx1);
    }
#pragma unroll
    for (int ii = 0; ii < 4; ++ii)
#pragma unroll
      for (int jj = 0; jj < 2; ++jj) {
        acc[ii][2 + jj] = MFMA16(a0[ii][0], b1[jj][0], acc[ii][2 + jj]);
        acc[ii][2 + jj] = MFMA16(a0[ii][1], b1[jj][1], acc[ii][2 + jj]);
      }
    // group 3: A rows 64-127 -> acc[4..7][2..3]
    f16x8 a1[4][2];
#pragma unroll
    for (int ii = 0; ii < 4; ++ii) {
      a1[ii][0] = *(const f16x8*)(As + (4 + ii) * 2048 + aoff + gx0);
      a1[ii][1] = *(const f16x8*)(As + (4 + ii) * 2048 + aoff + gx1);
    }
#pragma unroll
    for (int ii = 0; ii < 4; ++ii)
#pragma unroll
      for (int jj = 0; jj < 2; ++jj) {
        acc[4 + ii][2 + jj] = MFMA16(a1[ii][0], b1[jj][0], acc[4 + ii][2 + jj]);
        acc[4 + ii][2 + jj] = MFMA16(a1[ii][1], b1[jj][1], acc[4 + ii][2 + jj]);
      }
    // group 4: reuse b0 from regs -> acc[4..7][0..1] (no reads)
#pragma unroll
    for (int ii = 0; ii < 4; ++ii)
#pragma unroll
      for (int jj = 0; jj < 2; ++jj) {
        acc[4 + ii][jj] = MFMA16(a1[ii][0], b0[jj][0], acc[4 + ii][jj]);
        acc[4 + ii][jj] = MFMA16(a1[ii][1], b0[jj][1], acc[4 + ii][jj]);
      }
    // next tile's stages were issued ~full tile ago -> drain is cheap
    asm volatile("s_waitcnt vmcnt(0)" ::: "memory");
    SCHED0();
    SBAR(); SCHED0();
  }
#undef STA
#undef STB
}

// ---------------- k_score: E = exp(invn * (bnnH @ embH^T)) ---------------
__global__ __launch_bounds__(512, 2) void k_score(const f16* __restrict__ A,
                                                  const f16* __restrict__ Bt,
                                                  const float* __restrict__ invn,
                                                  u16* __restrict__ E,
                                                  float* __restrict__ lpart,
                                                  int row0, int CH) {
  extern __shared__ char lds[];
  const int t = threadIdx.x;
  const int l = t & 63, lr = l & 15, lg = l >> 4;
  const int w = t >> 6, wm = w >> 2, wn = w & 3;
  const int mB = CH >> 8;
  const int nwg = NB2 * mB;
  const int o = blockIdx.x + blockIdx.y * gridDim.x;
  const int qd = nwg >> 3, r = nwg & 7;
  const int xcd = o & 7, idx = o >> 3;
  const int v = (xcd < r ? xcd * (qd + 1) : r * (qd + 1) + (xcd - r) * qd) + idx;
  const int nb = v % NB2, by = v / NB2;
  const int n0 = nb * 256;
  const int mloc = by * 256;

  f32x4 acc[8][4];
#pragma unroll
  for (int i = 0; i < 8; ++i)
#pragma unroll
    for (int j = 0; j < 4; ++j) acc[i][j] = (f32x4){0.f, 0.f, 0.f, 0.f};

  gemm_kloop(A, Bt, DT, DT, 0, DT / 64, row0 + mloc, n0, lds, t, acc);

  // ---- epilogue: exp, bounce to LDS (reused), coalesced E store, row sums
  float* psum = (float*)(lds + 131072);
  float inv_j[4];
#pragma unroll
  for (int j = 0; j < 4; ++j) inv_j[j] = invn[n0 + wn * 64 + j * 16 + lr];
#pragma unroll
  for (int i = 0; i < 8; ++i) {
#pragma unroll
    for (int rg = 0; rg < 4; ++rg) {
      int row = wm * 128 + i * 16 + lg * 4 + rg;
      float rs = 0.f;
#pragma unroll
      for (int j = 0; j < 4; ++j) {
        float e = __expf(acc[i][j][rg] * inv_j[j]);
        rs += e;
        int col = wn * 64 + j * 16 + lr;
        int g4 = col >> 3;
        *(u16*)(lds + row * 512 + ((g4 ^ lg) << 4) + (col & 7) * 2) = f2h(e);
      }
#pragma unroll
      for (int m = 1; m <= 8; m <<= 1) rs += __shfl_xor(rs, m);
      if (lr == 0) psum[w * 128 + i * 16 + lg * 4 + rg] = rs;
    }
  }
  __syncthreads();
#pragma unroll
  for (int cc = 0; cc < 16; ++cc) {
    int lin = cc * 512 + t;
    int row = lin >> 5, g4 = lin & 31;
    int4 vv = *(const int4*)(lds + row * 512 + ((g4 ^ ((row >> 2) & 3)) << 4));
    *(int4*)&E[(size_t)(mloc + row) * NV + n0 + g4 * 8] = vv;
  }
  if (t < 256) {
    int wmx = t >> 7, rl = t & 127;
    float s = psum[(wmx * 4 + 0) * 128 + rl] + psum[(wmx * 4 + 1) * 128 + rl] +
              psum[(wmx * 4 + 2) * 128 + rl] + psum[(wmx * 4 + 3) * 128 + rl];
    lpart[(size_t)nb * CH + mloc + t] = s;
  }
}

// ---------------- k_pv: Op[z] = E @ embT^T (uneven K-split) --------------
__global__ __launch_bounds__(512, 2) void k_pv(const f16* __restrict__ A,
                                               const f16* __restrict__ Bt,
                                               float* __restrict__ Op,
                                               int CH) {
  extern __shared__ char lds[];
  const int t = threadIdx.x;
  const int l = t & 63, lr = l & 15, lg = l >> 4;
  const int w = t >> 6, wm = w >> 2, wn = w & 3;
  const int n0 = blockIdx.x * 256;
  const int mloc = blockIdx.y * 256;
  const int z = blockIdx.z;
  const int g0 = z * 48 + (z < 4 ? z : 4);
  const int NT = 48 + (z < 4 ? 1 : 0);
  const size_t kb = (size_t)g0 * 64;

  f32x4 acc[8][4];
#pragma unroll
  for (int i = 0; i < 8; ++i)
#pragma unroll
    for (int j = 0; j < 4; ++j) acc[i][j] = (f32x4){0.f, 0.f, 0.f, 0.f};

  gemm_kloop(A, Bt, NV, NV, kb, NT, mloc, n0, lds, t, acc);

#pragma unroll
  for (int i = 0; i < 8; ++i)
#pragma unroll
    for (int j = 0; j < 4; ++j)
#pragma unroll
      for (int rg = 0; rg < 4; ++rg) {
        int row = mloc + wm * 128 + i * 16 + lg * 4 + rg;
        int col = n0 + wn * 64 + j * 16 + lr;
        Op[((size_t)z * CH + row) * DT + col] = acc[i][j][rg];
      }
}

// ---------------- l[r] = sum over vocab of E -----------------------------
__global__ __launch_bounds__(256) void k_lred(const float* __restrict__ lp,
                                              float* __restrict__ lv, int CH) {
  int rb = blockIdx.x * 256 + threadIdx.x;
  float s = 0.f;
  for (int nb = 0; nb < NB2; ++nb) s += lp[(size_t)nb * CH + rb];
  lv[rb] = s;
}

// ---------------- combine split-K + divide by l --------------------------
__global__ __launch_bounds__(256) void k_out(const float* __restrict__ Op,
                                             const float* __restrict__ lv,
                                             float* __restrict__ out,
                                             int row0, int CH) {
  int idx = blockIdx.x * 256 + threadIdx.x;
  int rb = idx >> 9, c = idx & 511;
  float s = 0.f;
#pragma unroll
  for (int zz = 0; zz < KS; ++zz) s += Op[((size_t)zz * CH + rb) * DT + c];
  out[(size_t)(row0 + rb) * DT + c] = s / lv[rb];
}

extern "C" void kernel_launch(void* const* d_in, const int* in_sizes, int n_in,
                              void* d_out, int out_size, void* d_ws, size_t ws_size,
                              hipStream_t stream) {
  const float* audio = (const float*)d_in[0];
  const float* W     = (const float*)d_in[1];
  const float* bias  = (const float*)d_in[2];
  const float* gamma = (const float*)d_in[3];
  const float* beta  = (const float*)d_in[4];
  const float* emb   = (const float*)d_in[5];
  float* out = (float*)d_out;

  char* ws = (char*)d_ws;
  size_t off = 0;
  auto alloc = [&](size_t bytes) {
    char* p = ws + off;
    off += (bytes + 255) & ~(size_t)255;
    return p;
  };
  float* proj  = (float*)alloc((size_t)MTOT * DT * 4);
  float* pstat = (float*)alloc((size_t)64 * 1024 * 4);
  float* stats = (float*)alloc((size_t)2 * DT * 4);
  u16*   bnnH  = (u16*)alloc((size_t)MTOT * DT * 2);
  u16*   embH  = (u16*)alloc((size_t)NV * DT * 2);
  u16*   embT  = (u16*)alloc((size_t)DT * NV * 2);
  float* invn  = (float*)alloc((size_t)NV * 4);
  size_t fixed_off = off;

  int CH = 2048;
  while (CH > 256) {
    size_t need = fixed_off;
    need += (((size_t)CH * NV * 2) + 255) & ~(size_t)255;          // E
    need += (((size_t)NB2 * CH * 4) + 255) & ~(size_t)255;         // lpart
    need += (((size_t)CH * 4) + 255) & ~(size_t)255;               // lvec
    need += (((size_t)KS * CH * DT * 4) + 255) & ~(size_t)255;     // Op
    if (need <= ws_size) break;
    CH >>= 1;
  }
  u16*   E     = (u16*)alloc((size_t)CH * NV * 2);
  float* lpart = (float*)alloc((size_t)NB2 * CH * 4);
  float* lvec  = (float*)alloc((size_t)CH * 4);
  float* Op    = (float*)alloc((size_t)KS * CH * DT * 4);
  if (ws_size < off) return;

  hipFuncSetAttribute((const void*)k_score,
                      hipFuncAttributeMaxDynamicSharedMemorySize, 135168);
  hipFuncSetAttribute((const void*)k_pv,
                      hipFuncAttributeMaxDynamicSharedMemorySize, 131072);

  k_proj<<<dim3(32, 8), dim3(256), 0, stream>>>(audio, W, bias, proj);
  k_stats<<<dim3(64), dim3(256), 0, stream>>>(proj, pstat);
  k_stats2<<<dim3(4), dim3(256), 0, stream>>>(pstat, stats);
  k_bnnorm<<<dim3(MTOT), dim3(64), 0, stream>>>(proj, stats, gamma, beta, bnnH);
  k_embprep2<<<dim3(NV / 64), dim3(256), 0, stream>>>(emb, embH, embT, invn);

  for (int row0 = 0; row0 < MTOT; row0 += CH) {
    k_score<<<dim3(NB2, CH / 256), dim3(512), 135168, stream>>>(
        (const f16*)bnnH, (const f16*)embH, invn, E, lpart, row0, CH);
    k_lred<<<dim3(CH / 256), dim3(256), 0, stream>>>(lpart, lvec, CH);
    k_pv<<<dim3(2, CH / 256, KS), dim3(512), 131072, stream>>>(
        (const f16*)E, (const f16*)embT, Op, CH);
    k_out<<<dim3(CH * 2), dim3(256), 0, stream>>>(Op, lvec, out, row0, CH);
  }
}